// Round 18
// baseline (487.575 us; speedup 1.0000x reference)
//
#include <hip/hip_runtime.h>
#include <cstdint>

#define N_NODES 100000
#define EP_N 400000
#define EN_N 400000
#define NODE_BLOCKS ((N_NODES + 63) / 64)
#define DEEP_BLOCKS (N_NODES / 32)
#define SCHUNK 512
#define SBLK ((N_NODES + SCHUNK - 1) / SCHUNK)

#define BSTR 264
#define DSTR 392

#define XB_BLKS ((((N_NODES + 1) * 16) + 255) / 256)
#define WP_BLKS 113
#define CNT_BLKS (((EP_N + EN_N) + 255) / 256)

// ws layout (in 4-byte units)
#define ACC_OFF 0
#define I_CNTP 16
#define I_CNTN (I_CNTP + N_NODES)
#define I_CURP (I_CNTN + N_NODES)
#define I_CURN (I_CURP + N_NODES)
#define I_OFFP (I_CURN + N_NODES)
#define I_OFFN (I_OFFP + N_NODES + 1)
#define I_OFFPC (I_OFFN + N_NODES + 1)
#define I_OFFNC (I_OFFPC + N_NODES + 1)
#define I_CSRP (((I_OFFNC + N_NODES + 1) + 3) & ~3)
#define CSR_SZ (EP_N + 4 * N_NODES)
#define I_CSRN (I_CSRP + CSR_SZ)
#define I_PART (I_CSRN + CSR_SZ)
#define I_EIDX (((I_PART + 4 * SBLK) + 3) & ~3)
#define F_XB (((I_EIDX + 4 * (EP_N + EN_N)) + 15) & ~15)
#define F_HB (F_XB + 32 * (N_NODES + 1))
#define F_HQ (F_HB + 64 * (N_NODES + 1))
#define F_PNU (F_HQ + 32 * (N_NODES + 1))
#define F_ZQ (F_PNU + 4 * N_NODES)
#define F_WT (((F_ZQ + 16 * N_NODES) + 15) & ~15)

typedef __attribute__((ext_vector_type(8))) short sh8;
typedef __attribute__((ext_vector_type(4))) float f32x4;

__device__ inline float bf2f(unsigned short u) {
    return __uint_as_float((unsigned)u << 16);
}
__device__ inline unsigned short f2bf(float v) {
    unsigned u = __float_as_uint(v);
    return (unsigned short)((u + 0x7FFFu + ((u >> 16) & 1u)) >> 16);
}
__device__ inline float lo_bf(unsigned u) { return __uint_as_float(u << 16); }
__device__ inline float hi_bf(unsigned u) { return __uint_as_float(u & 0xFFFF0000u); }

// process one dword (4 fp8 vals) of i/j/k rows + packed W v-col pairs:
// accumulate d1 += fi*fj, d2 += fj*fk, sj += fj^2, sk += fk^2, v0/v1 += fj*w
#define F8_STEP(T)                                                        \
    {                                                                     \
        float fi = __builtin_amdgcn_cvt_f32_fp8(ui, T);                   \
        float fj = __builtin_amdgcn_cvt_f32_fp8(uj, T);                   \
        float fk = __builtin_amdgcn_cvt_f32_fp8(uk, T);                   \
        d1 = fmaf(fi, fj, d1);                                            \
        d2 = fmaf(fj, fk, d2);                                            \
        sj = fmaf(fj, fj, sj);                                            \
        sk = fmaf(fk, fk, sk);                                            \
        unsigned wp = (&wvv.x)[T];                                        \
        v0 = fmaf(fj, lo_bf(wp), v0);                                     \
        v1 = fmaf(fj, hi_bf(wp), v1);                                     \
    }

__device__ inline void f8chunk(unsigned ui, unsigned uj, unsigned uk, uint4 wvv,
                               float& d1, float& d2, float& sj, float& sk,
                               float& v0, float& v1) {
    F8_STEP(0)
    F8_STEP(1)
    F8_STEP(2)
    F8_STEP(3)
}

// fused: X->bf16 (+sentinel) | weight transpose->bf16 (+Wreg v-cols) | degree count
__global__ void prep_kernel(const float* __restrict__ X, unsigned short* __restrict__ xb,
                            const float* __restrict__ W0p, const float* __restrict__ W0n,
                            const float* __restrict__ W1p, const float* __restrict__ W1n,
                            const float* __restrict__ Wreg,
                            unsigned short* __restrict__ wt,
                            const int* __restrict__ pe, const int* __restrict__ ne,
                            int* cp, int* cn) {
    int b = blockIdx.x;
    if (b < XB_BLKS) {
        int i = b * 256 + threadIdx.x;
        if (i < (N_NODES + 1) * 16) {
            ushort4 o = {0, 0, 0, 0};
            if (i < N_NODES * 16) {
                float4 v = ((const float4*)X)[i];
                o.x = f2bf(v.x); o.y = f2bf(v.y); o.z = f2bf(v.z); o.w = f2bf(v.w);
            }
            ((ushort4*)xb)[i] = o;
        }
    } else if (b < XB_BLKS + WP_BLKS) {
        int i = (b - XB_BLKS) * 256 + threadIdx.x;
        if (i < 8192) {
            int n = i >> 7, k = i & 127;
            wt[i] = f2bf(W0p[k * 64 + n]);
        } else if (i < 16384) {
            int j = i - 8192; int n = j >> 7, k = j & 127;
            wt[i] = f2bf(W0n[k * 64 + n]);
        } else if (i < 22528) {
            int j = i - 16384; int n = j / 192, k = j - n * 192;
            wt[i] = f2bf(W1p[k * 32 + n]);
        } else if (i < 28672) {
            int j = i - 22528; int n = j / 192, k = j - n * 192;
            wt[i] = f2bf(W1n[k * 32 + n]);
        } else if (i < 28736) {
            int j = i - 28672;
            unsigned* wvb = (unsigned*)(wt + 28672);
            wvb[j] = (unsigned)f2bf(Wreg[128 + j * 2]) |
                     ((unsigned)f2bf(Wreg[128 + j * 2 + 1]) << 16);
        }
    } else {
        int i = (b - XB_BLKS - WP_BLKS) * 256 + threadIdx.x;
        if (i < EP_N) {
            atomicAdd(&cp[pe[i]], 1);
        } else if (i < EP_N + EN_N) {
            atomicAdd(&cn[ne[i - EP_N]], 1);
        }
    }
}

__global__ __launch_bounds__(512) void scan_p1(const int* __restrict__ cntP,
                                               const int* __restrict__ cntN,
                                               int* part) {
    int l = blockIdx.x < SBLK ? 0 : 1;
    int blk = blockIdx.x - l * SBLK;
    const int* cnt = l == 0 ? cntP : cntN;
    int idx = blk * SCHUNK + threadIdx.x;
    int c = idx < N_NODES ? cnt[idx] : 0;
    int vp = (c + 3) & ~3;
    __shared__ int tmp[512];
    __shared__ int tmp2[512];
    tmp[threadIdx.x] = vp;
    tmp2[threadIdx.x] = c;
    __syncthreads();
    for (int d = 256; d > 0; d >>= 1) {
        if (threadIdx.x < d) {
            tmp[threadIdx.x] += tmp[threadIdx.x + d];
            tmp2[threadIdx.x] += tmp2[threadIdx.x + d];
        }
        __syncthreads();
    }
    if (threadIdx.x == 0) {
        part[l * SBLK + blk] = tmp[0];
        part[(2 + l) * SBLK + blk] = tmp2[0];
    }
}

__global__ __launch_bounds__(1024) void scan_p2(int* part) {
    int t = threadIdx.x;
    int l = t >> 8, idx = t & 255;
    int v = idx < SBLK ? part[l * SBLK + idx] : 0;
    __shared__ int tmp[1024];
    int sb = l << 8;
    tmp[sb + idx] = v;
    __syncthreads();
    for (int d = 1; d < 256; d <<= 1) {
        int x = (idx >= d) ? tmp[sb + idx - d] : 0;
        __syncthreads();
        tmp[sb + idx] += x;
        __syncthreads();
    }
    if (idx < SBLK) part[l * SBLK + idx] = tmp[sb + idx] - v;
}

__global__ __launch_bounds__(512) void scan_p3(const int* __restrict__ cntP,
                                               const int* __restrict__ cntN,
                                               const int* __restrict__ part,
                                               int* offP, int* offN,
                                               int* offPc, int* offNc,
                                               int* csrP, int* csrN) {
    int l = blockIdx.x < SBLK ? 0 : 1;
    int blk = blockIdx.x - l * SBLK;
    const int* cnt = l == 0 ? cntP : cntN;
    int* off = l == 0 ? offP : offN;
    int* offc = l == 0 ? offPc : offNc;
    int* csr = l == 0 ? csrP : csrN;
    int base = part[l * SBLK + blk];
    int basec = part[(2 + l) * SBLK + blk];
    int t = threadIdx.x;
    int gidx = blk * SCHUNK + t;
    int c = gidx < N_NODES ? cnt[gidx] : 0;
    int cpad = (c + 3) & ~3;
    __shared__ int tmp[512];
    __shared__ int tmp2[512];
    tmp[t] = cpad;
    tmp2[t] = c;
    __syncthreads();
    for (int d = 1; d < 512; d <<= 1) {
        int x = (t >= d) ? tmp[t - d] : 0;
        int x2 = (t >= d) ? tmp2[t - d] : 0;
        __syncthreads();
        tmp[t] += x;
        tmp2[t] += x2;
        __syncthreads();
    }
    int incl = tmp[t], inclc = tmp2[t];
    if (gidx < N_NODES) {
        int o = base + incl - cpad;
        off[gidx] = o;
        offc[gidx] = basec + inclc - c;
        for (int p = c; p < cpad; ++p) csr[o + p] = N_NODES;
    }
    if (gidx == N_NODES - 1) {
        off[N_NODES] = base + incl;
        offc[N_NODES] = basec + inclc;
    }
}

__global__ void fill_kernel(const int* __restrict__ pe, const int* __restrict__ ne,
                            const int* __restrict__ offP, const int* __restrict__ offN,
                            const int* __restrict__ offPc, const int* __restrict__ offNc,
                            const int* __restrict__ ps, const int* __restrict__ ns,
                            const int* __restrict__ tgt,
                            int* curP, int* curN, int* csrP, int* csrN,
                            int4* __restrict__ eidx) {
    int e = blockIdx.x * 256 + threadIdx.x;
    if (e < EP_N) {
        int row = pe[e], col = pe[EP_N + e];
        int slot = atomicAdd(&curP[row], 1);
        csrP[offP[row] + slot] = col;
        int4 q = {row, col, ps[e], tgt[e]};
        eidx[offPc[row] + slot] = q;
    } else if (e < EP_N + EN_N) {
        int e2 = e - EP_N;
        int row = ne[e2], col = ne[EN_N + e2];
        int slot = atomicAdd(&curN[row], 1);
        csrN[offN[row] + slot] = col;
        int4 q = {row, col, ns[e2], tgt[e]};
        eidx[EP_N + offNc[row] + slot] = q;
    }
}

__device__ inline void gmb2w(const unsigned* __restrict__ xb32,
                             const int* __restrict__ csrP, int pP, int enP, int cP,
                             const int* __restrict__ csrN, int pN, int enN, int cN,
                             int hf, int l5,
                             float& gP0, float& gP1, float& gN0, float& gN1) {
    float a0 = 0.f, a1 = 0.f, b0 = 0.f, b1 = 0.f;
    while (pP < enP && pN < enN) {
        int4 ca = *(const int4*)(csrP + pP);
        int4 cb = *(const int4*)(csrN + pN);
        int cA0 = hf ? ca.y : ca.x;
        int cA1 = hf ? ca.w : ca.z;
        int cB0 = hf ? cb.y : cb.x;
        int cB1 = hf ? cb.w : cb.z;
        unsigned va0 = xb32[cA0 * 32 + l5];
        unsigned va1 = xb32[cA1 * 32 + l5];
        unsigned vb0 = xb32[cB0 * 32 + l5];
        unsigned vb1 = xb32[cB1 * 32 + l5];
        a0 += lo_bf(va0) + lo_bf(va1);
        a1 += hi_bf(va0) + hi_bf(va1);
        b0 += lo_bf(vb0) + lo_bf(vb1);
        b1 += hi_bf(vb0) + hi_bf(vb1);
        pP += 4; pN += 4;
    }
    for (; pP < enP; pP += 4) {
        int4 ca = *(const int4*)(csrP + pP);
        int cA0 = hf ? ca.y : ca.x;
        int cA1 = hf ? ca.w : ca.z;
        unsigned va0 = xb32[cA0 * 32 + l5];
        unsigned va1 = xb32[cA1 * 32 + l5];
        a0 += lo_bf(va0) + lo_bf(va1);
        a1 += hi_bf(va0) + hi_bf(va1);
    }
    for (; pN < enN; pN += 4) {
        int4 cb = *(const int4*)(csrN + pN);
        int cB0 = hf ? cb.y : cb.x;
        int cB1 = hf ? cb.w : cb.z;
        unsigned vb0 = xb32[cB0 * 32 + l5];
        unsigned vb1 = xb32[cB1 * 32 + l5];
        b0 += lo_bf(vb0) + lo_bf(vb1);
        b1 += hi_bf(vb0) + hi_bf(vb1);
    }
    a0 += __shfl_xor(a0, 32); a1 += __shfl_xor(a1, 32);
    b0 += __shfl_xor(b0, 32); b1 += __shfl_xor(b1, 32);
    float rP = 1.f / fmaxf((float)cP, 1.f), rN = 1.f / fmaxf((float)cN, 1.f);
    gP0 = a0 * rP; gP1 = a1 * rP;
    gN0 = b0 * rN; gN1 = b1 * rN;
}

__device__ inline void gd2q(const unsigned* __restrict__ hq32,
                            const int* __restrict__ csrP, int pP, int enP, int cP,
                            const int* __restrict__ csrN, int pN, int enN, int cN,
                            int hf, int l5,
                            float& gPp0, float& gPp1, float& gPn0, float& gPn1,
                            float& gNp0, float& gNp1, float& gNn0, float& gNn1) {
    float ap0 = 0.f, ap1 = 0.f, an0 = 0.f, an1 = 0.f;
    float bp0 = 0.f, bp1 = 0.f, bn0 = 0.f, bn1 = 0.f;
    while (pP < enP && pN < enN) {
        int4 ca = *(const int4*)(csrP + pP);
        int4 cb = *(const int4*)(csrN + pN);
        int cA0 = hf ? ca.y : ca.x;
        int cA1 = hf ? ca.w : ca.z;
        int cB0 = hf ? cb.y : cb.x;
        int cB1 = hf ? cb.w : cb.z;
        unsigned va0 = hq32[cA0 * 32 + l5];
        unsigned va1 = hq32[cA1 * 32 + l5];
        unsigned vb0 = hq32[cB0 * 32 + l5];
        unsigned vb1 = hq32[cB1 * 32 + l5];
        ap0 += __builtin_amdgcn_cvt_f32_fp8(va0, 0) + __builtin_amdgcn_cvt_f32_fp8(va1, 0);
        an0 += __builtin_amdgcn_cvt_f32_fp8(va0, 1) + __builtin_amdgcn_cvt_f32_fp8(va1, 1);
        ap1 += __builtin_amdgcn_cvt_f32_fp8(va0, 2) + __builtin_amdgcn_cvt_f32_fp8(va1, 2);
        an1 += __builtin_amdgcn_cvt_f32_fp8(va0, 3) + __builtin_amdgcn_cvt_f32_fp8(va1, 3);
        bp0 += __builtin_amdgcn_cvt_f32_fp8(vb0, 0) + __builtin_amdgcn_cvt_f32_fp8(vb1, 0);
        bn0 += __builtin_amdgcn_cvt_f32_fp8(vb0, 1) + __builtin_amdgcn_cvt_f32_fp8(vb1, 1);
        bp1 += __builtin_amdgcn_cvt_f32_fp8(vb0, 2) + __builtin_amdgcn_cvt_f32_fp8(vb1, 2);
        bn1 += __builtin_amdgcn_cvt_f32_fp8(vb0, 3) + __builtin_amdgcn_cvt_f32_fp8(vb1, 3);
        pP += 4; pN += 4;
    }
    for (; pP < enP; pP += 4) {
        int4 ca = *(const int4*)(csrP + pP);
        int cA0 = hf ? ca.y : ca.x;
        int cA1 = hf ? ca.w : ca.z;
        unsigned va0 = hq32[cA0 * 32 + l5];
        unsigned va1 = hq32[cA1 * 32 + l5];
        ap0 += __builtin_amdgcn_cvt_f32_fp8(va0, 0) + __builtin_amdgcn_cvt_f32_fp8(va1, 0);
        an0 += __builtin_amdgcn_cvt_f32_fp8(va0, 1) + __builtin_amdgcn_cvt_f32_fp8(va1, 1);
        ap1 += __builtin_amdgcn_cvt_f32_fp8(va0, 2) + __builtin_amdgcn_cvt_f32_fp8(va1, 2);
        an1 += __builtin_amdgcn_cvt_f32_fp8(va0, 3) + __builtin_amdgcn_cvt_f32_fp8(va1, 3);
    }
    for (; pN < enN; pN += 4) {
        int4 cb = *(const int4*)(csrN + pN);
        int cB0 = hf ? cb.y : cb.x;
        int cB1 = hf ? cb.w : cb.z;
        unsigned vb0 = hq32[cB0 * 32 + l5];
        unsigned vb1 = hq32[cB1 * 32 + l5];
        bp0 += __builtin_amdgcn_cvt_f32_fp8(vb0, 0) + __builtin_amdgcn_cvt_f32_fp8(vb1, 0);
        bn0 += __builtin_amdgcn_cvt_f32_fp8(vb0, 1) + __builtin_amdgcn_cvt_f32_fp8(vb1, 1);
        bp1 += __builtin_amdgcn_cvt_f32_fp8(vb0, 2) + __builtin_amdgcn_cvt_f32_fp8(vb1, 2);
        bn1 += __builtin_amdgcn_cvt_f32_fp8(vb0, 3) + __builtin_amdgcn_cvt_f32_fp8(vb1, 3);
    }
    ap0 += __shfl_xor(ap0, 32); ap1 += __shfl_xor(ap1, 32);
    an0 += __shfl_xor(an0, 32); an1 += __shfl_xor(an1, 32);
    bp0 += __shfl_xor(bp0, 32); bp1 += __shfl_xor(bp1, 32);
    bn0 += __shfl_xor(bn0, 32); bn1 += __shfl_xor(bn1, 32);
    float rP = 1.f / fmaxf((float)cP, 1.f), rN = 1.f / fmaxf((float)cN, 1.f);
    gPp0 = ap0 * rP; gPp1 = ap1 * rP; gPn0 = an0 * rP; gPn1 = an1 * rP;
    gNp0 = bp0 * rN; gNp1 = bp1 * rN; gNn0 = bn0 * rN; gNn1 = bn1 * rN;
}

__global__ __launch_bounds__(512) void base_both(
    const unsigned short* __restrict__ xb,
    const int* __restrict__ offP, const int* __restrict__ csrP,
    const int* __restrict__ offN, const int* __restrict__ csrN,
    const int* __restrict__ cntP, const int* __restrict__ cntN,
    const unsigned short* __restrict__ wt0,
    const float* __restrict__ bp0, const float* __restrict__ bn0,
    unsigned short* __restrict__ hboth, unsigned* __restrict__ hq32) {
    __shared__ unsigned short lds[64 * BSTR];
    int tid = threadIdx.x, lane = tid & 63, w = tid >> 6;
    int hf = lane >> 5, l5 = lane & 31;
    int base = blockIdx.x * 64;
    const unsigned* xb32 = (const unsigned*)xb;
    if (blockIdx.x == 0 && tid < 64) ((unsigned*)hboth)[N_NODES * 64 + tid] = 0u;
    if (blockIdx.x == 0 && tid < 32) hq32[N_NODES * 32 + tid] = 0u;
    for (int r = w * 8; r < w * 8 + 8; ++r) {
        int node = base + r;
        float gP0 = 0.f, gP1 = 0.f, gN0 = 0.f, gN1 = 0.f;
        unsigned sxv = 0;
        if (node < N_NODES) {
            gmb2w(xb32, csrP, offP[node], offP[node + 1], cntP[node],
                  csrN, offN[node], offN[node + 1], cntN[node], hf, l5,
                  gP0, gP1, gN0, gN1);
            sxv = xb32[node * 32 + l5];
        }
        unsigned* rp32 = (unsigned*)&lds[r * BSTR];
        if (hf == 0) {
            rp32[l5] = (unsigned)f2bf(gP0) | ((unsigned)f2bf(gP1) << 16);
            rp32[32 + l5] = sxv;
        } else {
            rp32[64 + l5] = (unsigned)f2bf(gN0) | ((unsigned)f2bf(gN1) << 16);
            rp32[96 + l5] = sxv;
        }
    }
    __syncthreads();
    int wu = __builtin_amdgcn_readfirstlane(w);
    int mt = wu >> 1, half = wu & 1;
    int l15 = lane & 15, kq = lane >> 4;
    const unsigned short* wbase = wt0 + half * 8192;
    f32x4 acc[4];
#pragma unroll
    for (int nt = 0; nt < 4; ++nt) acc[nt] = (f32x4){0.f, 0.f, 0.f, 0.f};
    const unsigned short* arow = &lds[(mt * 16 + l15) * BSTR + half * 128 + kq * 8];
#pragma unroll
    for (int ks = 0; ks < 4; ++ks) {
        sh8 a = *(const sh8*)(arow + ks * 32);
#pragma unroll
        for (int nt = 0; nt < 4; ++nt) {
            sh8 bf = *(const sh8*)(wbase + (nt * 16 + l15) * 128 + ks * 32 + kq * 8);
            acc[nt] = __builtin_amdgcn_mfma_f32_16x16x32_bf16(a, bf, acc[nt], 0, 0, 0);
        }
    }
    __syncthreads();
    float* ht = (float*)lds;  // [64][130]
    const float* bias = half ? bn0 : bp0;
#pragma unroll
    for (int nt = 0; nt < 4; ++nt) {
        int col = nt * 16 + l15;
        float bb = bias[col];
#pragma unroll
        for (int r = 0; r < 4; ++r) {
            int row = mt * 16 + kq * 4 + r;
            ht[row * 130 + half * 64 + col] = tanhf(acc[nt][r] + bb);
        }
    }
    __syncthreads();
    unsigned* hb32 = (unsigned*)hboth;
    for (int i = tid; i < 64 * 64; i += 512) {
        int rr = i >> 6, c = i & 63;
        int node = base + rr;
        if (node < N_NODES) {
            unsigned lo = f2bf(ht[rr * 130 + c]);
            unsigned hi = f2bf(ht[rr * 130 + 64 + c]);
            hb32[node * 64 + c] = lo | (hi << 16);
        }
    }
    for (int i = tid; i < 64 * 32; i += 512) {
        int rr = i >> 5, c2 = i & 31;
        int node = base + rr;
        if (node < N_NODES) {
            float hp0 = ht[rr * 130 + 2 * c2];
            float hn0 = ht[rr * 130 + 64 + 2 * c2];
            float hp1 = ht[rr * 130 + 2 * c2 + 1];
            float hn1 = ht[rr * 130 + 64 + 2 * c2 + 1];
            int lo = __builtin_amdgcn_cvt_pk_fp8_f32(hp0, hn0, 0, false);
            int q = __builtin_amdgcn_cvt_pk_fp8_f32(hp1, hn1, lo, true);
            hq32[node * 32 + c2] = (unsigned)q;
        }
    }
}

__global__ __launch_bounds__(512) void deep_both(
    const unsigned short* __restrict__ hb, const unsigned* __restrict__ hq32,
    const int* __restrict__ offP, const int* __restrict__ csrP,
    const int* __restrict__ offN, const int* __restrict__ csrN,
    const int* __restrict__ cntP, const int* __restrict__ cntN,
    const unsigned short* __restrict__ wt1,
    const float* __restrict__ bp1, const float* __restrict__ bn1,
    const float* __restrict__ Wreg, float* __restrict__ z,
    unsigned char* __restrict__ zq, float4* __restrict__ pnu) {
    __shared__ unsigned short lds[32 * DSTR];
    int tid = threadIdx.x, lane = tid & 63, w = tid >> 6;
    int hf = lane >> 5, l5 = lane & 31;
    int base = blockIdx.x * 32;
    const unsigned* hb32 = (const unsigned*)hb;
    for (int r = w * 4; r < w * 4 + 4; ++r) {
        int node = base + r;
        float gPp0, gPp1, gPn0, gPn1, gNp0, gNp1, gNn0, gNn1;
        gd2q(hq32, csrP, offP[node], offP[node + 1], cntP[node],
             csrN, offN[node], offN[node + 1], cntN[node], hf, l5,
             gPp0, gPp1, gPn0, gPn1, gNp0, gNp1, gNn0, gNn1);
        uint2 sv = *(const uint2*)(hb32 + node * 64 + l5 * 2);
        unsigned* rp32 = (unsigned*)&lds[r * DSTR];
        if (hf == 0) {
            rp32[l5] = (unsigned)f2bf(gPp0) | ((unsigned)f2bf(gPp1) << 16);
            rp32[32 + l5] = (unsigned)f2bf(gNn0) | ((unsigned)f2bf(gNn1) << 16);
            rp32[64 + l5] = (sv.x & 0xFFFFu) | ((sv.y & 0xFFFFu) << 16);
        } else {
            rp32[96 + l5] = (unsigned)f2bf(gPn0) | ((unsigned)f2bf(gPn1) << 16);
            rp32[128 + l5] = (unsigned)f2bf(gNp0) | ((unsigned)f2bf(gNp1) << 16);
            rp32[160 + l5] = (sv.x >> 16) | (sv.y & 0xFFFF0000u);
        }
    }
    __syncthreads();
    int wu = __builtin_amdgcn_readfirstlane(w);
    int mt = wu >> 2, half = (wu >> 1) & 1, nt = wu & 1;
    int l15 = lane & 15, kq = lane >> 4;
    const unsigned short* wbase = wt1 + half * 6144;
    f32x4 acc = (f32x4){0.f, 0.f, 0.f, 0.f};
    const unsigned short* arow = &lds[(mt * 16 + l15) * DSTR + half * 192 + kq * 8];
#pragma unroll
    for (int ks = 0; ks < 6; ++ks) {
        sh8 a = *(const sh8*)(arow + ks * 32);
        sh8 bf = *(const sh8*)(wbase + (nt * 16 + l15) * 192 + ks * 32 + kq * 8);
        acc = __builtin_amdgcn_mfma_f32_16x16x32_bf16(a, bf, acc, 0, 0, 0);
    }
    __syncthreads();
    float* ot = (float*)lds;  // [32][65]
    {
        const float* bias = half ? bn1 : bp1;
        int col = nt * 16 + l15;
        float bb = bias[col];
#pragma unroll
        for (int r = 0; r < 4; ++r) {
            int row = mt * 16 + kq * 4 + r;
            ot[row * 65 + half * 32 + col] = tanhf(acc[r] + bb);
        }
    }
    __syncthreads();
    for (int r = w * 4; r < w * 4 + 4; ++r) {
        int node = base + r;
        float v = ot[r * 65 + lane];
        z[node * 64 + lane] = v;
        int pq = __builtin_amdgcn_cvt_pk_fp8_f32(v, v, 0, false);
        zq[node * 64 + lane] = (unsigned char)(pq & 0xFF);
        float vq = __builtin_amdgcn_cvt_f32_fp8(pq, 0);
        float u0 = vq * Wreg[lane * 2 + 0];
        float u1 = vq * Wreg[lane * 2 + 1];
        float s = vq * vq;
#pragma unroll
        for (int off = 32; off; off >>= 1) {
            u0 += __shfl_xor(u0, off);
            u1 += __shfl_xor(u1, off);
            s += __shfl_xor(s, off);
        }
        if (lane == 0) {
            float4 su = {u0, u1, s, 0.f};
            pnu[node] = su;
        }
    }
}

// 4-lane edge groups, chunked fp8 conversion (low VGPR), forced 6 blocks/CU
__global__ __launch_bounds__(256, 6) void loss8_kernel(
    const unsigned char* __restrict__ zq, const float4* __restrict__ pnu,
    const unsigned* __restrict__ wvb, const int4* __restrict__ eidx, float* acc) {
    int tid = threadIdx.x;
    int lane = tid & 63;
    int g = lane >> 2, sub = lane & 3;
    int wid = (blockIdx.x * 256 + tid) >> 6;
    int nw = (gridDim.x * 256) >> 6;
    uint4 wv4[4];
#pragma unroll
    for (int t = 0; t < 4; ++t) wv4[t] = ((const uint4*)wvb)[sub * 4 + t];
    float s_p = 0.f, s_n = 0.f, s_r = 0.f;
    const float q = 0.25f;
    for (int eb = wid * 32; eb < EP_N + EN_N; eb += nw * 32) {
        int eA = eb + g, eB = eb + 16 + g;
        bool vA = eA < EP_N + EN_N, vB = eB < EP_N + EN_N;
        bool pA = eA < EP_N, pB = eB < EP_N;
        int4 qA = eidx[vA ? eA : 0];
        int4 qB = eidx[vB ? eB : 0];
        uint4 ziA = *(const uint4*)(zq + ((long long)qA.x << 6) + (sub << 4));
        uint4 zjA = *(const uint4*)(zq + ((long long)qA.y << 6) + (sub << 4));
        uint4 zkA = *(const uint4*)(zq + ((long long)qA.z << 6) + (sub << 4));
        uint4 ziB = *(const uint4*)(zq + ((long long)qB.x << 6) + (sub << 4));
        uint4 zjB = *(const uint4*)(zq + ((long long)qB.y << 6) + (sub << 4));
        uint4 zkB = *(const uint4*)(zq + ((long long)qB.z << 6) + (sub << 4));
        float4 uA = pnu[qA.x];
        float4 uB = pnu[qB.x];
        float d1A = 0.f, d2A = 0.f, sjA = 0.f, skA = 0.f, v0A = 0.f, v1A = 0.f;
        f8chunk(ziA.x, zjA.x, zkA.x, wv4[0], d1A, d2A, sjA, skA, v0A, v1A);
        f8chunk(ziA.y, zjA.y, zkA.y, wv4[1], d1A, d2A, sjA, skA, v0A, v1A);
        f8chunk(ziA.z, zjA.z, zkA.z, wv4[2], d1A, d2A, sjA, skA, v0A, v1A);
        f8chunk(ziA.w, zjA.w, zkA.w, wv4[3], d1A, d2A, sjA, skA, v0A, v1A);
        float d1B = 0.f, d2B = 0.f, sjB = 0.f, skB = 0.f, v0B = 0.f, v1B = 0.f;
        f8chunk(ziB.x, zjB.x, zkB.x, wv4[0], d1B, d2B, sjB, skB, v0B, v1B);
        f8chunk(ziB.y, zjB.y, zkB.y, wv4[1], d1B, d2B, sjB, skB, v0B, v1B);
        f8chunk(ziB.z, zjB.z, zkB.z, wv4[2], d1B, d2B, sjB, skB, v0B, v1B);
        f8chunk(ziB.w, zjB.w, zkB.w, wv4[3], d1B, d2B, sjB, skB, v0B, v1B);
#pragma unroll
        for (int off = 1; off < 4; off <<= 1) {
            d1A += __shfl_xor(d1A, off);
            d2A += __shfl_xor(d2A, off);
            sjA += __shfl_xor(sjA, off);
            skA += __shfl_xor(skA, off);
            v0A += __shfl_xor(v0A, off);
            v1A += __shfl_xor(v1A, off);
            d1B += __shfl_xor(d1B, off);
            d2B += __shfl_xor(d2B, off);
            sjB += __shfl_xor(sjB, off);
            skB += __shfl_xor(skB, off);
            v0B += __shfl_xor(v0B, off);
            v1B += __shfl_xor(v1B, off);
        }
        if (vA) {
            float nij = uA.z + sjA - 2.f * d1A;
            float nik = sjA + skA - 2.f * d2A;
            float tri = fmaxf(nij - nik, 0.f);
            float l0 = uA.x + v0A, l1 = uA.y + v1A;
            float m = fmaxf(l0, l1);
            float lse = m + logf(expf(l0 - m) + expf(l1 - m));
            s_r += (lse - (qA.w ? l1 : l0)) * q;
            if (pA) s_p += tri * q; else s_n += tri * q;
        }
        if (vB) {
            float nij = uB.z + sjB - 2.f * d1B;
            float nik = sjB + skB - 2.f * d2B;
            float tri = fmaxf(nij - nik, 0.f);
            float l0 = uB.x + v0B, l1 = uB.y + v1B;
            float m = fmaxf(l0, l1);
            float lse = m + logf(expf(l0 - m) + expf(l1 - m));
            s_r += (lse - (qB.w ? l1 : l0)) * q;
            if (pB) s_p += tri * q; else s_n += tri * q;
        }
    }
#pragma unroll
    for (int off = 32; off; off >>= 1) {
        s_p += __shfl_xor(s_p, off);
        s_n += __shfl_xor(s_n, off);
        s_r += __shfl_xor(s_r, off);
    }
    __shared__ float red[3][4];
    int w = tid >> 6;
    if (lane == 0) {
        red[0][w] = s_p; red[1][w] = s_n; red[2][w] = s_r;
    }
    __syncthreads();
    if (tid == 0) {
        atomicAdd(&acc[0], red[0][0] + red[0][1] + red[0][2] + red[0][3]);
        atomicAdd(&acc[1], red[1][0] + red[1][1] + red[1][2] + red[1][3]);
        atomicAdd(&acc[2], red[2][0] + red[2][1] + red[2][2] + red[2][3]);
    }
}

__global__ void finalize_kernel(const float* __restrict__ acc, float* out) {
    out[0] = acc[2] / (float)(EP_N + EN_N) +
             1.0f * (acc[0] / (float)EP_N + acc[1] / (float)EN_N);
}

extern "C" void kernel_launch(void* const* d_in, const int* in_sizes, int n_in,
                              void* d_out, int out_size, void* d_ws, size_t ws_size,
                              hipStream_t stream) {
    const float* X = (const float*)d_in[0];
    const float* W_pos0 = (const float*)d_in[1];
    const float* b_pos0 = (const float*)d_in[2];
    const float* W_neg0 = (const float*)d_in[3];
    const float* b_neg0 = (const float*)d_in[4];
    const float* W_pos1 = (const float*)d_in[5];
    const float* b_pos1 = (const float*)d_in[6];
    const float* W_neg1 = (const float*)d_in[7];
    const float* b_neg1 = (const float*)d_in[8];
    const float* W_reg = (const float*)d_in[9];
    const int* pe = (const int*)d_in[10];
    const int* ne = (const int*)d_in[11];
    const int* target = (const int*)d_in[12];
    const int* ps = (const int*)d_in[13];
    const int* ns = (const int*)d_in[14];
    float* out = (float*)d_out;
    float* ws = (float*)d_ws;
    int* wsi = (int*)d_ws;

    float* acc = ws + ACC_OFF;
    int* cntP = wsi + I_CNTP;
    int* cntN = wsi + I_CNTN;
    int* curP = wsi + I_CURP;
    int* curN = wsi + I_CURN;
    int* offP = wsi + I_OFFP;
    int* offN = wsi + I_OFFN;
    int* offPc = wsi + I_OFFPC;
    int* offNc = wsi + I_OFFNC;
    int* csrP = wsi + I_CSRP;
    int* csrN = wsi + I_CSRN;
    int* part = wsi + I_PART;
    int4* eidx = (int4*)(wsi + I_EIDX);
    unsigned short* xb = (unsigned short*)(ws + F_XB);
    unsigned short* hboth = (unsigned short*)(ws + F_HB);
    unsigned* hq32 = (unsigned*)(ws + F_HQ);
    float4* pnu = (float4*)(ws + F_PNU);
    unsigned char* zq = (unsigned char*)(ws + F_ZQ);
    unsigned short* wt = (unsigned short*)(ws + F_WT);
    const unsigned* wvb = (const unsigned*)(wt + 28672);
    float* z = out + 1;

    hipMemsetAsync(ws, 0, (size_t)(16 + 4 * N_NODES) * sizeof(float), stream);

    prep_kernel<<<XB_BLKS + WP_BLKS + CNT_BLKS, 256, 0, stream>>>(
        X, xb, W_pos0, W_neg0, W_pos1, W_neg1, W_reg, wt, pe, ne, cntP, cntN);
    scan_p1<<<2 * SBLK, 512, 0, stream>>>(cntP, cntN, part);
    scan_p2<<<1, 1024, 0, stream>>>(part);
    scan_p3<<<2 * SBLK, 512, 0, stream>>>(cntP, cntN, part, offP, offN,
                                          offPc, offNc, csrP, csrN);
    fill_kernel<<<(EP_N + EN_N + 255) / 256, 256, 0, stream>>>(
        pe, ne, offP, offN, offPc, offNc, ps, ns, target,
        curP, curN, csrP, csrN, eidx);

    base_both<<<NODE_BLOCKS, 512, 0, stream>>>(xb, offP, csrP, offN, csrN, cntP, cntN,
                                               wt, b_pos0, b_neg0, hboth, hq32);
    deep_both<<<DEEP_BLOCKS, 512, 0, stream>>>(hboth, hq32, offP, csrP, offN, csrN,
                                               cntP, cntN, wt + 16384, b_pos1, b_neg1,
                                               W_reg, z, zq, pnu);

    loss8_kernel<<<4096, 256, 0, stream>>>(zq, pnu, wvb, eidx, acc);
    finalize_kernel<<<1, 1, 0, stream>>>(acc, out);
}

// Round 19
// 412.112 us; speedup vs baseline: 1.1831x; 1.1831x over previous
//
#include <hip/hip_runtime.h>
#include <cstdint>

#define N_NODES 100000
#define EP_N 400000
#define EN_N 400000
#define NODE_BLOCKS ((N_NODES + 63) / 64)
#define DEEP_BLOCKS (N_NODES / 32)
#define SCHUNK 512
#define SBLK ((N_NODES + SCHUNK - 1) / SCHUNK)

#define BSTR 264
#define DSTR 392

#define XB_BLKS ((((N_NODES + 1) * 16) + 255) / 256)
#define WP_BLKS 113
#define CNT_BLKS (((EP_N + EN_N) + 255) / 256)

// ws layout (in 4-byte units)
#define ACC_OFF 0
#define I_CNTP 16
#define I_CNTN (I_CNTP + N_NODES)
#define I_CURP (I_CNTN + N_NODES)
#define I_CURN (I_CURP + N_NODES)
#define I_OFFP (I_CURN + N_NODES)
#define I_OFFN (I_OFFP + N_NODES + 1)
#define I_OFFPC (I_OFFN + N_NODES + 1)
#define I_OFFNC (I_OFFPC + N_NODES + 1)
#define I_CSRP (((I_OFFNC + N_NODES + 1) + 3) & ~3)
#define CSR_SZ (EP_N + 4 * N_NODES)
#define I_CSRN (I_CSRP + CSR_SZ)
#define I_PART (I_CSRN + CSR_SZ)
#define I_EIDX (((I_PART + 4 * SBLK) + 3) & ~3)
#define F_XB (((I_EIDX + 4 * (EP_N + EN_N)) + 15) & ~15)
#define F_HB (F_XB + 32 * (N_NODES + 1))
#define F_HQ (F_HB + 64 * (N_NODES + 1))
#define F_PNU (F_HQ + 32 * (N_NODES + 1))
#define F_ZQ (F_PNU + 4 * N_NODES)
#define F_WT (((F_ZQ + 16 * N_NODES) + 15) & ~15)

typedef __attribute__((ext_vector_type(8))) short sh8;
typedef __attribute__((ext_vector_type(4))) float f32x4;

__device__ inline float bf2f(unsigned short u) {
    return __uint_as_float((unsigned)u << 16);
}
__device__ inline unsigned short f2bf(float v) {
    unsigned u = __float_as_uint(v);
    return (unsigned short)((u + 0x7FFFu + ((u >> 16) & 1u)) >> 16);
}
__device__ inline float lo_bf(unsigned u) { return __uint_as_float(u << 16); }
__device__ inline float hi_bf(unsigned u) { return __uint_as_float(u & 0xFFFF0000u); }

// process one dword (4 fp8 vals) of i/j/k rows + packed W v-col pairs
#define F8_STEP(T)                                                        \
    {                                                                     \
        float fi = __builtin_amdgcn_cvt_f32_fp8(ui, T);                   \
        float fj = __builtin_amdgcn_cvt_f32_fp8(uj, T);                   \
        float fk = __builtin_amdgcn_cvt_f32_fp8(uk, T);                   \
        d1 = fmaf(fi, fj, d1);                                            \
        d2 = fmaf(fj, fk, d2);                                            \
        sj = fmaf(fj, fj, sj);                                            \
        sk = fmaf(fk, fk, sk);                                            \
        unsigned wp = (&wvv.x)[T];                                        \
        v0 = fmaf(fj, lo_bf(wp), v0);                                     \
        v1 = fmaf(fj, hi_bf(wp), v1);                                     \
    }

__device__ inline void f8chunk(unsigned ui, unsigned uj, unsigned uk, uint4 wvv,
                               float& d1, float& d2, float& sj, float& sk,
                               float& v0, float& v1) {
    F8_STEP(0)
    F8_STEP(1)
    F8_STEP(2)
    F8_STEP(3)
}

// fused: X->bf16 (+sentinel) | weight transpose->bf16 (+Wreg v-cols) | degree count
__global__ void prep_kernel(const float* __restrict__ X, unsigned short* __restrict__ xb,
                            const float* __restrict__ W0p, const float* __restrict__ W0n,
                            const float* __restrict__ W1p, const float* __restrict__ W1n,
                            const float* __restrict__ Wreg,
                            unsigned short* __restrict__ wt,
                            const int* __restrict__ pe, const int* __restrict__ ne,
                            int* cp, int* cn) {
    int b = blockIdx.x;
    if (b < XB_BLKS) {
        int i = b * 256 + threadIdx.x;
        if (i < (N_NODES + 1) * 16) {
            ushort4 o = {0, 0, 0, 0};
            if (i < N_NODES * 16) {
                float4 v = ((const float4*)X)[i];
                o.x = f2bf(v.x); o.y = f2bf(v.y); o.z = f2bf(v.z); o.w = f2bf(v.w);
            }
            ((ushort4*)xb)[i] = o;
        }
    } else if (b < XB_BLKS + WP_BLKS) {
        int i = (b - XB_BLKS) * 256 + threadIdx.x;
        if (i < 8192) {
            int n = i >> 7, k = i & 127;
            wt[i] = f2bf(W0p[k * 64 + n]);
        } else if (i < 16384) {
            int j = i - 8192; int n = j >> 7, k = j & 127;
            wt[i] = f2bf(W0n[k * 64 + n]);
        } else if (i < 22528) {
            int j = i - 16384; int n = j / 192, k = j - n * 192;
            wt[i] = f2bf(W1p[k * 32 + n]);
        } else if (i < 28672) {
            int j = i - 22528; int n = j / 192, k = j - n * 192;
            wt[i] = f2bf(W1n[k * 32 + n]);
        } else if (i < 28736) {
            int j = i - 28672;
            unsigned* wvb = (unsigned*)(wt + 28672);
            wvb[j] = (unsigned)f2bf(Wreg[128 + j * 2]) |
                     ((unsigned)f2bf(Wreg[128 + j * 2 + 1]) << 16);
        }
    } else {
        int i = (b - XB_BLKS - WP_BLKS) * 256 + threadIdx.x;
        if (i < EP_N) {
            atomicAdd(&cp[pe[i]], 1);
        } else if (i < EP_N + EN_N) {
            atomicAdd(&cn[ne[i - EP_N]], 1);
        }
    }
}

__global__ __launch_bounds__(512) void scan_p1(const int* __restrict__ cntP,
                                               const int* __restrict__ cntN,
                                               int* part) {
    int l = blockIdx.x < SBLK ? 0 : 1;
    int blk = blockIdx.x - l * SBLK;
    const int* cnt = l == 0 ? cntP : cntN;
    int idx = blk * SCHUNK + threadIdx.x;
    int c = idx < N_NODES ? cnt[idx] : 0;
    int vp = (c + 3) & ~3;
    __shared__ int tmp[512];
    __shared__ int tmp2[512];
    tmp[threadIdx.x] = vp;
    tmp2[threadIdx.x] = c;
    __syncthreads();
    for (int d = 256; d > 0; d >>= 1) {
        if (threadIdx.x < d) {
            tmp[threadIdx.x] += tmp[threadIdx.x + d];
            tmp2[threadIdx.x] += tmp2[threadIdx.x + d];
        }
        __syncthreads();
    }
    if (threadIdx.x == 0) {
        part[l * SBLK + blk] = tmp[0];
        part[(2 + l) * SBLK + blk] = tmp2[0];
    }
}

__global__ __launch_bounds__(1024) void scan_p2(int* part) {
    int t = threadIdx.x;
    int l = t >> 8, idx = t & 255;
    int v = idx < SBLK ? part[l * SBLK + idx] : 0;
    __shared__ int tmp[1024];
    int sb = l << 8;
    tmp[sb + idx] = v;
    __syncthreads();
    for (int d = 1; d < 256; d <<= 1) {
        int x = (idx >= d) ? tmp[sb + idx - d] : 0;
        __syncthreads();
        tmp[sb + idx] += x;
        __syncthreads();
    }
    if (idx < SBLK) part[l * SBLK + idx] = tmp[sb + idx] - v;
}

__global__ __launch_bounds__(512) void scan_p3(const int* __restrict__ cntP,
                                               const int* __restrict__ cntN,
                                               const int* __restrict__ part,
                                               int* offP, int* offN,
                                               int* offPc, int* offNc,
                                               int* csrP, int* csrN) {
    int l = blockIdx.x < SBLK ? 0 : 1;
    int blk = blockIdx.x - l * SBLK;
    const int* cnt = l == 0 ? cntP : cntN;
    int* off = l == 0 ? offP : offN;
    int* offc = l == 0 ? offPc : offNc;
    int* csr = l == 0 ? csrP : csrN;
    int base = part[l * SBLK + blk];
    int basec = part[(2 + l) * SBLK + blk];
    int t = threadIdx.x;
    int gidx = blk * SCHUNK + t;
    int c = gidx < N_NODES ? cnt[gidx] : 0;
    int cpad = (c + 3) & ~3;
    __shared__ int tmp[512];
    __shared__ int tmp2[512];
    tmp[t] = cpad;
    tmp2[t] = c;
    __syncthreads();
    for (int d = 1; d < 512; d <<= 1) {
        int x = (t >= d) ? tmp[t - d] : 0;
        int x2 = (t >= d) ? tmp2[t - d] : 0;
        __syncthreads();
        tmp[t] += x;
        tmp2[t] += x2;
        __syncthreads();
    }
    int incl = tmp[t], inclc = tmp2[t];
    if (gidx < N_NODES) {
        int o = base + incl - cpad;
        off[gidx] = o;
        offc[gidx] = basec + inclc - c;
        for (int p = c; p < cpad; ++p) csr[o + p] = N_NODES;
    }
    if (gidx == N_NODES - 1) {
        off[N_NODES] = base + incl;
        offc[N_NODES] = basec + inclc;
    }
}

__global__ void fill_kernel(const int* __restrict__ pe, const int* __restrict__ ne,
                            const int* __restrict__ offP, const int* __restrict__ offN,
                            const int* __restrict__ offPc, const int* __restrict__ offNc,
                            const int* __restrict__ ps, const int* __restrict__ ns,
                            const int* __restrict__ tgt,
                            int* curP, int* curN, int* csrP, int* csrN,
                            int4* __restrict__ eidx) {
    int e = blockIdx.x * 256 + threadIdx.x;
    if (e < EP_N) {
        int row = pe[e], col = pe[EP_N + e];
        int slot = atomicAdd(&curP[row], 1);
        csrP[offP[row] + slot] = col;
        int4 q = {row, col, ps[e], tgt[e]};
        eidx[offPc[row] + slot] = q;
    } else if (e < EP_N + EN_N) {
        int e2 = e - EP_N;
        int row = ne[e2], col = ne[EN_N + e2];
        int slot = atomicAdd(&curN[row], 1);
        csrN[offN[row] + slot] = col;
        int4 q = {row, col, ns[e2], tgt[e]};
        eidx[EP_N + offNc[row] + slot] = q;
    }
}

__device__ inline void gmb2w(const unsigned* __restrict__ xb32,
                             const int* __restrict__ csrP, int pP, int enP, int cP,
                             const int* __restrict__ csrN, int pN, int enN, int cN,
                             int hf, int l5,
                             float& gP0, float& gP1, float& gN0, float& gN1) {
    float a0 = 0.f, a1 = 0.f, b0 = 0.f, b1 = 0.f;
    while (pP < enP && pN < enN) {
        int4 ca = *(const int4*)(csrP + pP);
        int4 cb = *(const int4*)(csrN + pN);
        int cA0 = hf ? ca.y : ca.x;
        int cA1 = hf ? ca.w : ca.z;
        int cB0 = hf ? cb.y : cb.x;
        int cB1 = hf ? cb.w : cb.z;
        unsigned va0 = xb32[cA0 * 32 + l5];
        unsigned va1 = xb32[cA1 * 32 + l5];
        unsigned vb0 = xb32[cB0 * 32 + l5];
        unsigned vb1 = xb32[cB1 * 32 + l5];
        a0 += lo_bf(va0) + lo_bf(va1);
        a1 += hi_bf(va0) + hi_bf(va1);
        b0 += lo_bf(vb0) + lo_bf(vb1);
        b1 += hi_bf(vb0) + hi_bf(vb1);
        pP += 4; pN += 4;
    }
    for (; pP < enP; pP += 4) {
        int4 ca = *(const int4*)(csrP + pP);
        int cA0 = hf ? ca.y : ca.x;
        int cA1 = hf ? ca.w : ca.z;
        unsigned va0 = xb32[cA0 * 32 + l5];
        unsigned va1 = xb32[cA1 * 32 + l5];
        a0 += lo_bf(va0) + lo_bf(va1);
        a1 += hi_bf(va0) + hi_bf(va1);
    }
    for (; pN < enN; pN += 4) {
        int4 cb = *(const int4*)(csrN + pN);
        int cB0 = hf ? cb.y : cb.x;
        int cB1 = hf ? cb.w : cb.z;
        unsigned vb0 = xb32[cB0 * 32 + l5];
        unsigned vb1 = xb32[cB1 * 32 + l5];
        b0 += lo_bf(vb0) + lo_bf(vb1);
        b1 += hi_bf(vb0) + hi_bf(vb1);
    }
    a0 += __shfl_xor(a0, 32); a1 += __shfl_xor(a1, 32);
    b0 += __shfl_xor(b0, 32); b1 += __shfl_xor(b1, 32);
    float rP = 1.f / fmaxf((float)cP, 1.f), rN = 1.f / fmaxf((float)cN, 1.f);
    gP0 = a0 * rP; gP1 = a1 * rP;
    gN0 = b0 * rN; gN1 = b1 * rN;
}

__device__ inline void gd2q(const unsigned* __restrict__ hq32,
                            const int* __restrict__ csrP, int pP, int enP, int cP,
                            const int* __restrict__ csrN, int pN, int enN, int cN,
                            int hf, int l5,
                            float& gPp0, float& gPp1, float& gPn0, float& gPn1,
                            float& gNp0, float& gNp1, float& gNn0, float& gNn1) {
    float ap0 = 0.f, ap1 = 0.f, an0 = 0.f, an1 = 0.f;
    float bp0 = 0.f, bp1 = 0.f, bn0 = 0.f, bn1 = 0.f;
    while (pP < enP && pN < enN) {
        int4 ca = *(const int4*)(csrP + pP);
        int4 cb = *(const int4*)(csrN + pN);
        int cA0 = hf ? ca.y : ca.x;
        int cA1 = hf ? ca.w : ca.z;
        int cB0 = hf ? cb.y : cb.x;
        int cB1 = hf ? cb.w : cb.z;
        unsigned va0 = hq32[cA0 * 32 + l5];
        unsigned va1 = hq32[cA1 * 32 + l5];
        unsigned vb0 = hq32[cB0 * 32 + l5];
        unsigned vb1 = hq32[cB1 * 32 + l5];
        ap0 += __builtin_amdgcn_cvt_f32_fp8(va0, 0) + __builtin_amdgcn_cvt_f32_fp8(va1, 0);
        an0 += __builtin_amdgcn_cvt_f32_fp8(va0, 1) + __builtin_amdgcn_cvt_f32_fp8(va1, 1);
        ap1 += __builtin_amdgcn_cvt_f32_fp8(va0, 2) + __builtin_amdgcn_cvt_f32_fp8(va1, 2);
        an1 += __builtin_amdgcn_cvt_f32_fp8(va0, 3) + __builtin_amdgcn_cvt_f32_fp8(va1, 3);
        bp0 += __builtin_amdgcn_cvt_f32_fp8(vb0, 0) + __builtin_amdgcn_cvt_f32_fp8(vb1, 0);
        bn0 += __builtin_amdgcn_cvt_f32_fp8(vb0, 1) + __builtin_amdgcn_cvt_f32_fp8(vb1, 1);
        bp1 += __builtin_amdgcn_cvt_f32_fp8(vb0, 2) + __builtin_amdgcn_cvt_f32_fp8(vb1, 2);
        bn1 += __builtin_amdgcn_cvt_f32_fp8(vb0, 3) + __builtin_amdgcn_cvt_f32_fp8(vb1, 3);
        pP += 4; pN += 4;
    }
    for (; pP < enP; pP += 4) {
        int4 ca = *(const int4*)(csrP + pP);
        int cA0 = hf ? ca.y : ca.x;
        int cA1 = hf ? ca.w : ca.z;
        unsigned va0 = hq32[cA0 * 32 + l5];
        unsigned va1 = hq32[cA1 * 32 + l5];
        ap0 += __builtin_amdgcn_cvt_f32_fp8(va0, 0) + __builtin_amdgcn_cvt_f32_fp8(va1, 0);
        an0 += __builtin_amdgcn_cvt_f32_fp8(va0, 1) + __builtin_amdgcn_cvt_f32_fp8(va1, 1);
        ap1 += __builtin_amdgcn_cvt_f32_fp8(va0, 2) + __builtin_amdgcn_cvt_f32_fp8(va1, 2);
        an1 += __builtin_amdgcn_cvt_f32_fp8(va0, 3) + __builtin_amdgcn_cvt_f32_fp8(va1, 3);
    }
    for (; pN < enN; pN += 4) {
        int4 cb = *(const int4*)(csrN + pN);
        int cB0 = hf ? cb.y : cb.x;
        int cB1 = hf ? cb.w : cb.z;
        unsigned vb0 = hq32[cB0 * 32 + l5];
        unsigned vb1 = hq32[cB1 * 32 + l5];
        bp0 += __builtin_amdgcn_cvt_f32_fp8(vb0, 0) + __builtin_amdgcn_cvt_f32_fp8(vb1, 0);
        bn0 += __builtin_amdgcn_cvt_f32_fp8(vb0, 1) + __builtin_amdgcn_cvt_f32_fp8(vb1, 1);
        bp1 += __builtin_amdgcn_cvt_f32_fp8(vb0, 2) + __builtin_amdgcn_cvt_f32_fp8(vb1, 2);
        bn1 += __builtin_amdgcn_cvt_f32_fp8(vb0, 3) + __builtin_amdgcn_cvt_f32_fp8(vb1, 3);
    }
    ap0 += __shfl_xor(ap0, 32); ap1 += __shfl_xor(ap1, 32);
    an0 += __shfl_xor(an0, 32); an1 += __shfl_xor(an1, 32);
    bp0 += __shfl_xor(bp0, 32); bp1 += __shfl_xor(bp1, 32);
    bn0 += __shfl_xor(bn0, 32); bn1 += __shfl_xor(bn1, 32);
    float rP = 1.f / fmaxf((float)cP, 1.f), rN = 1.f / fmaxf((float)cN, 1.f);
    gPp0 = ap0 * rP; gPp1 = ap1 * rP; gPn0 = an0 * rP; gPn1 = an1 * rP;
    gNp0 = bp0 * rN; gNp1 = bp1 * rN; gNn0 = bn0 * rN; gNn1 = bn1 * rN;
}

__global__ __launch_bounds__(512) void base_both(
    const unsigned short* __restrict__ xb,
    const int* __restrict__ offP, const int* __restrict__ csrP,
    const int* __restrict__ offN, const int* __restrict__ csrN,
    const int* __restrict__ cntP, const int* __restrict__ cntN,
    const unsigned short* __restrict__ wt0,
    const float* __restrict__ bp0, const float* __restrict__ bn0,
    unsigned short* __restrict__ hboth, unsigned* __restrict__ hq32) {
    __shared__ unsigned short lds[64 * BSTR];
    int tid = threadIdx.x, lane = tid & 63, w = tid >> 6;
    int hf = lane >> 5, l5 = lane & 31;
    int base = blockIdx.x * 64;
    const unsigned* xb32 = (const unsigned*)xb;
    if (blockIdx.x == 0 && tid < 64) ((unsigned*)hboth)[N_NODES * 64 + tid] = 0u;
    if (blockIdx.x == 0 && tid < 32) hq32[N_NODES * 32 + tid] = 0u;
    for (int r = w * 8; r < w * 8 + 8; ++r) {
        int node = base + r;
        float gP0 = 0.f, gP1 = 0.f, gN0 = 0.f, gN1 = 0.f;
        unsigned sxv = 0;
        if (node < N_NODES) {
            gmb2w(xb32, csrP, offP[node], offP[node + 1], cntP[node],
                  csrN, offN[node], offN[node + 1], cntN[node], hf, l5,
                  gP0, gP1, gN0, gN1);
            sxv = xb32[node * 32 + l5];
        }
        unsigned* rp32 = (unsigned*)&lds[r * BSTR];
        if (hf == 0) {
            rp32[l5] = (unsigned)f2bf(gP0) | ((unsigned)f2bf(gP1) << 16);
            rp32[32 + l5] = sxv;
        } else {
            rp32[64 + l5] = (unsigned)f2bf(gN0) | ((unsigned)f2bf(gN1) << 16);
            rp32[96 + l5] = sxv;
        }
    }
    __syncthreads();
    int wu = __builtin_amdgcn_readfirstlane(w);
    int mt = wu >> 1, half = wu & 1;
    int l15 = lane & 15, kq = lane >> 4;
    const unsigned short* wbase = wt0 + half * 8192;
    f32x4 acc[4];
#pragma unroll
    for (int nt = 0; nt < 4; ++nt) acc[nt] = (f32x4){0.f, 0.f, 0.f, 0.f};
    const unsigned short* arow = &lds[(mt * 16 + l15) * BSTR + half * 128 + kq * 8];
#pragma unroll
    for (int ks = 0; ks < 4; ++ks) {
        sh8 a = *(const sh8*)(arow + ks * 32);
#pragma unroll
        for (int nt = 0; nt < 4; ++nt) {
            sh8 bf = *(const sh8*)(wbase + (nt * 16 + l15) * 128 + ks * 32 + kq * 8);
            acc[nt] = __builtin_amdgcn_mfma_f32_16x16x32_bf16(a, bf, acc[nt], 0, 0, 0);
        }
    }
    __syncthreads();
    float* ht = (float*)lds;  // [64][130]
    const float* bias = half ? bn0 : bp0;
#pragma unroll
    for (int nt = 0; nt < 4; ++nt) {
        int col = nt * 16 + l15;
        float bb = bias[col];
#pragma unroll
        for (int r = 0; r < 4; ++r) {
            int row = mt * 16 + kq * 4 + r;
            ht[row * 130 + half * 64 + col] = tanhf(acc[nt][r] + bb);
        }
    }
    __syncthreads();
    unsigned* hb32 = (unsigned*)hboth;
    for (int i = tid; i < 64 * 64; i += 512) {
        int rr = i >> 6, c = i & 63;
        int node = base + rr;
        if (node < N_NODES) {
            unsigned lo = f2bf(ht[rr * 130 + c]);
            unsigned hi = f2bf(ht[rr * 130 + 64 + c]);
            hb32[node * 64 + c] = lo | (hi << 16);
        }
    }
    for (int i = tid; i < 64 * 32; i += 512) {
        int rr = i >> 5, c2 = i & 31;
        int node = base + rr;
        if (node < N_NODES) {
            float hp0 = ht[rr * 130 + 2 * c2];
            float hn0 = ht[rr * 130 + 64 + 2 * c2];
            float hp1 = ht[rr * 130 + 2 * c2 + 1];
            float hn1 = ht[rr * 130 + 64 + 2 * c2 + 1];
            int lo = __builtin_amdgcn_cvt_pk_fp8_f32(hp0, hn0, 0, false);
            int q = __builtin_amdgcn_cvt_pk_fp8_f32(hp1, hn1, lo, true);
            hq32[node * 32 + c2] = (unsigned)q;
        }
    }
}

__global__ __launch_bounds__(512) void deep_both(
    const unsigned short* __restrict__ hb, const unsigned* __restrict__ hq32,
    const int* __restrict__ offP, const int* __restrict__ csrP,
    const int* __restrict__ offN, const int* __restrict__ csrN,
    const int* __restrict__ cntP, const int* __restrict__ cntN,
    const unsigned short* __restrict__ wt1,
    const float* __restrict__ bp1, const float* __restrict__ bn1,
    const float* __restrict__ Wreg, float* __restrict__ z,
    unsigned char* __restrict__ zq, float4* __restrict__ pnu) {
    __shared__ unsigned short lds[32 * DSTR];
    int tid = threadIdx.x, lane = tid & 63, w = tid >> 6;
    int hf = lane >> 5, l5 = lane & 31;
    int base = blockIdx.x * 32;
    const unsigned* hb32 = (const unsigned*)hb;
    for (int r = w * 4; r < w * 4 + 4; ++r) {
        int node = base + r;
        float gPp0, gPp1, gPn0, gPn1, gNp0, gNp1, gNn0, gNn1;
        gd2q(hq32, csrP, offP[node], offP[node + 1], cntP[node],
             csrN, offN[node], offN[node + 1], cntN[node], hf, l5,
             gPp0, gPp1, gPn0, gPn1, gNp0, gNp1, gNn0, gNn1);
        uint2 sv = *(const uint2*)(hb32 + node * 64 + l5 * 2);
        unsigned* rp32 = (unsigned*)&lds[r * DSTR];
        if (hf == 0) {
            rp32[l5] = (unsigned)f2bf(gPp0) | ((unsigned)f2bf(gPp1) << 16);
            rp32[32 + l5] = (unsigned)f2bf(gNn0) | ((unsigned)f2bf(gNn1) << 16);
            rp32[64 + l5] = (sv.x & 0xFFFFu) | ((sv.y & 0xFFFFu) << 16);
        } else {
            rp32[96 + l5] = (unsigned)f2bf(gPn0) | ((unsigned)f2bf(gPn1) << 16);
            rp32[128 + l5] = (unsigned)f2bf(gNp0) | ((unsigned)f2bf(gNp1) << 16);
            rp32[160 + l5] = (sv.x >> 16) | (sv.y & 0xFFFF0000u);
        }
    }
    __syncthreads();
    int wu = __builtin_amdgcn_readfirstlane(w);
    int mt = wu >> 2, half = (wu >> 1) & 1, nt = wu & 1;
    int l15 = lane & 15, kq = lane >> 4;
    const unsigned short* wbase = wt1 + half * 6144;
    f32x4 acc = (f32x4){0.f, 0.f, 0.f, 0.f};
    const unsigned short* arow = &lds[(mt * 16 + l15) * DSTR + half * 192 + kq * 8];
#pragma unroll
    for (int ks = 0; ks < 6; ++ks) {
        sh8 a = *(const sh8*)(arow + ks * 32);
        sh8 bf = *(const sh8*)(wbase + (nt * 16 + l15) * 192 + ks * 32 + kq * 8);
        acc = __builtin_amdgcn_mfma_f32_16x16x32_bf16(a, bf, acc, 0, 0, 0);
    }
    __syncthreads();
    float* ot = (float*)lds;  // [32][65]
    {
        const float* bias = half ? bn1 : bp1;
        int col = nt * 16 + l15;
        float bb = bias[col];
#pragma unroll
        for (int r = 0; r < 4; ++r) {
            int row = mt * 16 + kq * 4 + r;
            ot[row * 65 + half * 32 + col] = tanhf(acc[r] + bb);
        }
    }
    __syncthreads();
    for (int r = w * 4; r < w * 4 + 4; ++r) {
        int node = base + r;
        float v = ot[r * 65 + lane];
        z[node * 64 + lane] = v;
        int pq = __builtin_amdgcn_cvt_pk_fp8_f32(v, v, 0, false);
        zq[node * 64 + lane] = (unsigned char)(pq & 0xFF);
        float vq = __builtin_amdgcn_cvt_f32_fp8(pq, 0);
        float u0 = vq * Wreg[lane * 2 + 0];
        float u1 = vq * Wreg[lane * 2 + 1];
        float s = vq * vq;
#pragma unroll
        for (int off = 32; off; off >>= 1) {
            u0 += __shfl_xor(u0, off);
            u1 += __shfl_xor(u1, off);
            s += __shfl_xor(s, off);
        }
        if (lane == 0) {
            float4 su = {u0, u1, s, 0.f};
            pnu[node] = su;
        }
    }
}

// 4-lane edge groups, chunked fp8 conversion (natural VGPR allocation)
__global__ __launch_bounds__(256) void loss9_kernel(
    const unsigned char* __restrict__ zq, const float4* __restrict__ pnu,
    const unsigned* __restrict__ wvb, const int4* __restrict__ eidx, float* acc) {
    int tid = threadIdx.x;
    int lane = tid & 63;
    int g = lane >> 2, sub = lane & 3;
    int wid = (blockIdx.x * 256 + tid) >> 6;
    int nw = (gridDim.x * 256) >> 6;
    uint4 wv4[4];
#pragma unroll
    for (int t = 0; t < 4; ++t) wv4[t] = ((const uint4*)wvb)[sub * 4 + t];
    float s_p = 0.f, s_n = 0.f, s_r = 0.f;
    const float q = 0.25f;
    for (int eb = wid * 32; eb < EP_N + EN_N; eb += nw * 32) {
        int eA = eb + g, eB = eb + 16 + g;
        bool vA = eA < EP_N + EN_N, vB = eB < EP_N + EN_N;
        bool pA = eA < EP_N, pB = eB < EP_N;
        int4 qA = eidx[vA ? eA : 0];
        int4 qB = eidx[vB ? eB : 0];
        uint4 ziA = *(const uint4*)(zq + ((long long)qA.x << 6) + (sub << 4));
        uint4 zjA = *(const uint4*)(zq + ((long long)qA.y << 6) + (sub << 4));
        uint4 zkA = *(const uint4*)(zq + ((long long)qA.z << 6) + (sub << 4));
        uint4 ziB = *(const uint4*)(zq + ((long long)qB.x << 6) + (sub << 4));
        uint4 zjB = *(const uint4*)(zq + ((long long)qB.y << 6) + (sub << 4));
        uint4 zkB = *(const uint4*)(zq + ((long long)qB.z << 6) + (sub << 4));
        float4 uA = pnu[qA.x];
        float4 uB = pnu[qB.x];
        float d1A = 0.f, d2A = 0.f, sjA = 0.f, skA = 0.f, v0A = 0.f, v1A = 0.f;
        f8chunk(ziA.x, zjA.x, zkA.x, wv4[0], d1A, d2A, sjA, skA, v0A, v1A);
        f8chunk(ziA.y, zjA.y, zkA.y, wv4[1], d1A, d2A, sjA, skA, v0A, v1A);
        f8chunk(ziA.z, zjA.z, zkA.z, wv4[2], d1A, d2A, sjA, skA, v0A, v1A);
        f8chunk(ziA.w, zjA.w, zkA.w, wv4[3], d1A, d2A, sjA, skA, v0A, v1A);
        float d1B = 0.f, d2B = 0.f, sjB = 0.f, skB = 0.f, v0B = 0.f, v1B = 0.f;
        f8chunk(ziB.x, zjB.x, zkB.x, wv4[0], d1B, d2B, sjB, skB, v0B, v1B);
        f8chunk(ziB.y, zjB.y, zkB.y, wv4[1], d1B, d2B, sjB, skB, v0B, v1B);
        f8chunk(ziB.z, zjB.z, zkB.z, wv4[2], d1B, d2B, sjB, skB, v0B, v1B);
        f8chunk(ziB.w, zjB.w, zkB.w, wv4[3], d1B, d2B, sjB, skB, v0B, v1B);
#pragma unroll
        for (int off = 1; off < 4; off <<= 1) {
            d1A += __shfl_xor(d1A, off);
            d2A += __shfl_xor(d2A, off);
            sjA += __shfl_xor(sjA, off);
            skA += __shfl_xor(skA, off);
            v0A += __shfl_xor(v0A, off);
            v1A += __shfl_xor(v1A, off);
            d1B += __shfl_xor(d1B, off);
            d2B += __shfl_xor(d2B, off);
            sjB += __shfl_xor(sjB, off);
            skB += __shfl_xor(skB, off);
            v0B += __shfl_xor(v0B, off);
            v1B += __shfl_xor(v1B, off);
        }
        if (vA) {
            float nij = uA.z + sjA - 2.f * d1A;
            float nik = sjA + skA - 2.f * d2A;
            float tri = fmaxf(nij - nik, 0.f);
            float l0 = uA.x + v0A, l1 = uA.y + v1A;
            float m = fmaxf(l0, l1);
            float lse = m + logf(expf(l0 - m) + expf(l1 - m));
            s_r += (lse - (qA.w ? l1 : l0)) * q;
            if (pA) s_p += tri * q; else s_n += tri * q;
        }
        if (vB) {
            float nij = uB.z + sjB - 2.f * d1B;
            float nik = sjB + skB - 2.f * d2B;
            float tri = fmaxf(nij - nik, 0.f);
            float l0 = uB.x + v0B, l1 = uB.y + v1B;
            float m = fmaxf(l0, l1);
            float lse = m + logf(expf(l0 - m) + expf(l1 - m));
            s_r += (lse - (qB.w ? l1 : l0)) * q;
            if (pB) s_p += tri * q; else s_n += tri * q;
        }
    }
#pragma unroll
    for (int off = 32; off; off >>= 1) {
        s_p += __shfl_xor(s_p, off);
        s_n += __shfl_xor(s_n, off);
        s_r += __shfl_xor(s_r, off);
    }
    __shared__ float red[3][4];
    int w = tid >> 6;
    if (lane == 0) {
        red[0][w] = s_p; red[1][w] = s_n; red[2][w] = s_r;
    }
    __syncthreads();
    if (tid == 0) {
        atomicAdd(&acc[0], red[0][0] + red[0][1] + red[0][2] + red[0][3]);
        atomicAdd(&acc[1], red[1][0] + red[1][1] + red[1][2] + red[1][3]);
        atomicAdd(&acc[2], red[2][0] + red[2][1] + red[2][2] + red[2][3]);
    }
}

__global__ void finalize_kernel(const float* __restrict__ acc, float* out) {
    out[0] = acc[2] / (float)(EP_N + EN_N) +
             1.0f * (acc[0] / (float)EP_N + acc[1] / (float)EN_N);
}

extern "C" void kernel_launch(void* const* d_in, const int* in_sizes, int n_in,
                              void* d_out, int out_size, void* d_ws, size_t ws_size,
                              hipStream_t stream) {
    const float* X = (const float*)d_in[0];
    const float* W_pos0 = (const float*)d_in[1];
    const float* b_pos0 = (const float*)d_in[2];
    const float* W_neg0 = (const float*)d_in[3];
    const float* b_neg0 = (const float*)d_in[4];
    const float* W_pos1 = (const float*)d_in[5];
    const float* b_pos1 = (const float*)d_in[6];
    const float* W_neg1 = (const float*)d_in[7];
    const float* b_neg1 = (const float*)d_in[8];
    const float* W_reg = (const float*)d_in[9];
    const int* pe = (const int*)d_in[10];
    const int* ne = (const int*)d_in[11];
    const int* target = (const int*)d_in[12];
    const int* ps = (const int*)d_in[13];
    const int* ns = (const int*)d_in[14];
    float* out = (float*)d_out;
    float* ws = (float*)d_ws;
    int* wsi = (int*)d_ws;

    float* acc = ws + ACC_OFF;
    int* cntP = wsi + I_CNTP;
    int* cntN = wsi + I_CNTN;
    int* curP = wsi + I_CURP;
    int* curN = wsi + I_CURN;
    int* offP = wsi + I_OFFP;
    int* offN = wsi + I_OFFN;
    int* offPc = wsi + I_OFFPC;
    int* offNc = wsi + I_OFFNC;
    int* csrP = wsi + I_CSRP;
    int* csrN = wsi + I_CSRN;
    int* part = wsi + I_PART;
    int4* eidx = (int4*)(wsi + I_EIDX);
    unsigned short* xb = (unsigned short*)(ws + F_XB);
    unsigned short* hboth = (unsigned short*)(ws + F_HB);
    unsigned* hq32 = (unsigned*)(ws + F_HQ);
    float4* pnu = (float4*)(ws + F_PNU);
    unsigned char* zq = (unsigned char*)(ws + F_ZQ);
    unsigned short* wt = (unsigned short*)(ws + F_WT);
    const unsigned* wvb = (const unsigned*)(wt + 28672);
    float* z = out + 1;

    hipMemsetAsync(ws, 0, (size_t)(16 + 4 * N_NODES) * sizeof(float), stream);

    prep_kernel<<<XB_BLKS + WP_BLKS + CNT_BLKS, 256, 0, stream>>>(
        X, xb, W_pos0, W_neg0, W_pos1, W_neg1, W_reg, wt, pe, ne, cntP, cntN);
    scan_p1<<<2 * SBLK, 512, 0, stream>>>(cntP, cntN, part);
    scan_p2<<<1, 1024, 0, stream>>>(part);
    scan_p3<<<2 * SBLK, 512, 0, stream>>>(cntP, cntN, part, offP, offN,
                                          offPc, offNc, csrP, csrN);
    fill_kernel<<<(EP_N + EN_N + 255) / 256, 256, 0, stream>>>(
        pe, ne, offP, offN, offPc, offNc, ps, ns, target,
        curP, curN, csrP, csrN, eidx);

    base_both<<<NODE_BLOCKS, 512, 0, stream>>>(xb, offP, csrP, offN, csrN, cntP, cntN,
                                               wt, b_pos0, b_neg0, hboth, hq32);
    deep_both<<<DEEP_BLOCKS, 512, 0, stream>>>(hboth, hq32, offP, csrP, offN, csrN,
                                               cntP, cntN, wt + 16384, b_pos1, b_neg1,
                                               W_reg, z, zq, pnu);

    loss9_kernel<<<4096, 256, 0, stream>>>(zq, pnu, wvb, eidx, acc);
    finalize_kernel<<<1, 1, 0, stream>>>(acc, out);
}

// Round 20
// 331.808 us; speedup vs baseline: 1.4695x; 1.2420x over previous
//
#include <hip/hip_runtime.h>
#include <cstdint>

#define N_NODES 100000
#define EP_N 400000
#define EN_N 400000
#define NODE_BLOCKS ((N_NODES + 63) / 64)
#define DEEP_BLOCKS (N_NODES / 32)
#define SCHUNK 512
#define SBLK ((N_NODES + SCHUNK - 1) / SCHUNK)

#define BSTR 264
#define DSTR 392

#define XB_BLKS ((((N_NODES + 1) * 16) + 255) / 256)
#define WP_BLKS 113
#define CNT_BLKS (((EP_N + EN_N) + 255) / 256)

// ws layout (in 4-byte units)
#define ACC_OFF 0
#define I_CNTP 16
#define I_CNTN (I_CNTP + N_NODES)
#define I_CURP (I_CNTN + N_NODES)
#define I_CURN (I_CURP + N_NODES)
#define I_OFFP (I_CURN + N_NODES)
#define I_OFFN (I_OFFP + N_NODES + 1)
#define I_OFFPC (I_OFFN + N_NODES + 1)
#define I_OFFNC (I_OFFPC + N_NODES + 1)
#define I_CSRP (((I_OFFNC + N_NODES + 1) + 3) & ~3)
#define CSR_SZ (EP_N + 4 * N_NODES)
#define I_CSRN (I_CSRP + CSR_SZ)
#define I_PART (I_CSRN + CSR_SZ)
#define I_EIDX (((I_PART + 4 * SBLK) + 3) & ~3)
#define F_XB (((I_EIDX + 4 * (EP_N + EN_N)) + 15) & ~15)
#define F_HB (F_XB + 32 * (N_NODES + 1))
#define F_HQ (F_HB + 64 * (N_NODES + 1))
#define F_PNU (F_HQ + 32 * (N_NODES + 1))          // pnu: N float4 {u0,u1,s,0}
#define F_ZQ (F_PNU + 4 * N_NODES)                 // zq: N*64 bytes
#define F_WT (((F_ZQ + 16 * N_NODES) + 15) & ~15)  // wt: 28672 ushorts + 64 u32 wvb

typedef __attribute__((ext_vector_type(8))) short sh8;
typedef __attribute__((ext_vector_type(4))) float f32x4;

__device__ inline float bf2f(unsigned short u) {
    return __uint_as_float((unsigned)u << 16);
}
__device__ inline unsigned short f2bf(float v) {
    unsigned u = __float_as_uint(v);
    return (unsigned short)((u + 0x7FFFu + ((u >> 16) & 1u)) >> 16);
}
__device__ inline float lo_bf(unsigned u) { return __uint_as_float(u << 16); }
__device__ inline float hi_bf(unsigned u) { return __uint_as_float(u & 0xFFFF0000u); }

__device__ inline void cvt16(uint4 r, float* f) {
#pragma unroll
    for (int c = 0; c < 4; ++c) {
        unsigned u = (&r.x)[c];
        f[c * 4 + 0] = __builtin_amdgcn_cvt_f32_fp8(u, 0);
        f[c * 4 + 1] = __builtin_amdgcn_cvt_f32_fp8(u, 1);
        f[c * 4 + 2] = __builtin_amdgcn_cvt_f32_fp8(u, 2);
        f[c * 4 + 3] = __builtin_amdgcn_cvt_f32_fp8(u, 3);
    }
}

// fused: X->bf16 (+sentinel) | weight transpose->bf16 (+Wreg v-cols) | degree count
__global__ void prep_kernel(const float* __restrict__ X, unsigned short* __restrict__ xb,
                            const float* __restrict__ W0p, const float* __restrict__ W0n,
                            const float* __restrict__ W1p, const float* __restrict__ W1n,
                            const float* __restrict__ Wreg,
                            unsigned short* __restrict__ wt,
                            const int* __restrict__ pe, const int* __restrict__ ne,
                            int* cp, int* cn) {
    int b = blockIdx.x;
    if (b < XB_BLKS) {
        int i = b * 256 + threadIdx.x;
        if (i < (N_NODES + 1) * 16) {
            ushort4 o = {0, 0, 0, 0};
            if (i < N_NODES * 16) {
                float4 v = ((const float4*)X)[i];
                o.x = f2bf(v.x); o.y = f2bf(v.y); o.z = f2bf(v.z); o.w = f2bf(v.w);
            }
            ((ushort4*)xb)[i] = o;
        }
    } else if (b < XB_BLKS + WP_BLKS) {
        int i = (b - XB_BLKS) * 256 + threadIdx.x;
        if (i < 8192) {
            int n = i >> 7, k = i & 127;
            wt[i] = f2bf(W0p[k * 64 + n]);
        } else if (i < 16384) {
            int j = i - 8192; int n = j >> 7, k = j & 127;
            wt[i] = f2bf(W0n[k * 64 + n]);
        } else if (i < 22528) {
            int j = i - 16384; int n = j / 192, k = j - n * 192;
            wt[i] = f2bf(W1p[k * 32 + n]);
        } else if (i < 28672) {
            int j = i - 22528; int n = j / 192, k = j - n * 192;
            wt[i] = f2bf(W1n[k * 32 + n]);
        } else if (i < 28736) {
            int j = i - 28672;   // Wreg v-cols packed bf16: {v0,v1} per dim
            unsigned* wvb = (unsigned*)(wt + 28672);
            wvb[j] = (unsigned)f2bf(Wreg[128 + j * 2]) |
                     ((unsigned)f2bf(Wreg[128 + j * 2 + 1]) << 16);
        }
    } else {
        int i = (b - XB_BLKS - WP_BLKS) * 256 + threadIdx.x;
        if (i < EP_N) {
            atomicAdd(&cp[pe[i]], 1);
        } else if (i < EP_N + EN_N) {
            atomicAdd(&cn[ne[i - EP_N]], 1);
        }
    }
}

__global__ __launch_bounds__(512) void scan_p1(const int* __restrict__ cntP,
                                               const int* __restrict__ cntN,
                                               int* part) {
    int l = blockIdx.x < SBLK ? 0 : 1;
    int blk = blockIdx.x - l * SBLK;
    const int* cnt = l == 0 ? cntP : cntN;
    int idx = blk * SCHUNK + threadIdx.x;
    int c = idx < N_NODES ? cnt[idx] : 0;
    int vp = (c + 3) & ~3;
    __shared__ int tmp[512];
    __shared__ int tmp2[512];
    tmp[threadIdx.x] = vp;
    tmp2[threadIdx.x] = c;
    __syncthreads();
    for (int d = 256; d > 0; d >>= 1) {
        if (threadIdx.x < d) {
            tmp[threadIdx.x] += tmp[threadIdx.x + d];
            tmp2[threadIdx.x] += tmp2[threadIdx.x + d];
        }
        __syncthreads();
    }
    if (threadIdx.x == 0) {
        part[l * SBLK + blk] = tmp[0];
        part[(2 + l) * SBLK + blk] = tmp2[0];
    }
}

__global__ __launch_bounds__(1024) void scan_p2(int* part) {
    int t = threadIdx.x;
    int l = t >> 8, idx = t & 255;
    int v = idx < SBLK ? part[l * SBLK + idx] : 0;
    __shared__ int tmp[1024];
    int sb = l << 8;
    tmp[sb + idx] = v;
    __syncthreads();
    for (int d = 1; d < 256; d <<= 1) {
        int x = (idx >= d) ? tmp[sb + idx - d] : 0;
        __syncthreads();
        tmp[sb + idx] += x;
        __syncthreads();
    }
    if (idx < SBLK) part[l * SBLK + idx] = tmp[sb + idx] - v;
}

__global__ __launch_bounds__(512) void scan_p3(const int* __restrict__ cntP,
                                               const int* __restrict__ cntN,
                                               const int* __restrict__ part,
                                               int* offP, int* offN,
                                               int* offPc, int* offNc,
                                               int* csrP, int* csrN) {
    int l = blockIdx.x < SBLK ? 0 : 1;
    int blk = blockIdx.x - l * SBLK;
    const int* cnt = l == 0 ? cntP : cntN;
    int* off = l == 0 ? offP : offN;
    int* offc = l == 0 ? offPc : offNc;
    int* csr = l == 0 ? csrP : csrN;
    int base = part[l * SBLK + blk];
    int basec = part[(2 + l) * SBLK + blk];
    int t = threadIdx.x;
    int gidx = blk * SCHUNK + t;
    int c = gidx < N_NODES ? cnt[gidx] : 0;
    int cpad = (c + 3) & ~3;
    __shared__ int tmp[512];
    __shared__ int tmp2[512];
    tmp[t] = cpad;
    tmp2[t] = c;
    __syncthreads();
    for (int d = 1; d < 512; d <<= 1) {
        int x = (t >= d) ? tmp[t - d] : 0;
        int x2 = (t >= d) ? tmp2[t - d] : 0;
        __syncthreads();
        tmp[t] += x;
        tmp2[t] += x2;
        __syncthreads();
    }
    int incl = tmp[t], inclc = tmp2[t];
    if (gidx < N_NODES) {
        int o = base + incl - cpad;
        off[gidx] = o;
        offc[gidx] = basec + inclc - c;
        for (int p = c; p < cpad; ++p) csr[o + p] = N_NODES;
    }
    if (gidx == N_NODES - 1) {
        off[N_NODES] = base + incl;
        offc[N_NODES] = basec + inclc;
    }
}

__global__ void fill_kernel(const int* __restrict__ pe, const int* __restrict__ ne,
                            const int* __restrict__ offP, const int* __restrict__ offN,
                            const int* __restrict__ offPc, const int* __restrict__ offNc,
                            const int* __restrict__ ps, const int* __restrict__ ns,
                            const int* __restrict__ tgt,
                            int* curP, int* curN, int* csrP, int* csrN,
                            int4* __restrict__ eidx) {
    int e = blockIdx.x * 256 + threadIdx.x;
    if (e < EP_N) {
        int row = pe[e], col = pe[EP_N + e];
        int slot = atomicAdd(&curP[row], 1);
        csrP[offP[row] + slot] = col;
        int4 q = {row, col, ps[e], tgt[e]};
        eidx[offPc[row] + slot] = q;
    } else if (e < EP_N + EN_N) {
        int e2 = e - EP_N;
        int row = ne[e2], col = ne[EN_N + e2];
        int slot = atomicAdd(&curN[row], 1);
        csrN[offN[row] + slot] = col;
        int4 q = {row, col, ns[e2], tgt[e]};
        eidx[EP_N + offNc[row] + slot] = q;
    }
}

__device__ inline void gmb2w(const unsigned* __restrict__ xb32,
                             const int* __restrict__ csrP, int pP, int enP, int cP,
                             const int* __restrict__ csrN, int pN, int enN, int cN,
                             int hf, int l5,
                             float& gP0, float& gP1, float& gN0, float& gN1) {
    float a0 = 0.f, a1 = 0.f, b0 = 0.f, b1 = 0.f;
    while (pP < enP && pN < enN) {
        int4 ca = *(const int4*)(csrP + pP);
        int4 cb = *(const int4*)(csrN + pN);
        int cA0 = hf ? ca.y : ca.x;
        int cA1 = hf ? ca.w : ca.z;
        int cB0 = hf ? cb.y : cb.x;
        int cB1 = hf ? cb.w : cb.z;
        unsigned va0 = xb32[cA0 * 32 + l5];
        unsigned va1 = xb32[cA1 * 32 + l5];
        unsigned vb0 = xb32[cB0 * 32 + l5];
        unsigned vb1 = xb32[cB1 * 32 + l5];
        a0 += lo_bf(va0) + lo_bf(va1);
        a1 += hi_bf(va0) + hi_bf(va1);
        b0 += lo_bf(vb0) + lo_bf(vb1);
        b1 += hi_bf(vb0) + hi_bf(vb1);
        pP += 4; pN += 4;
    }
    for (; pP < enP; pP += 4) {
        int4 ca = *(const int4*)(csrP + pP);
        int cA0 = hf ? ca.y : ca.x;
        int cA1 = hf ? ca.w : ca.z;
        unsigned va0 = xb32[cA0 * 32 + l5];
        unsigned va1 = xb32[cA1 * 32 + l5];
        a0 += lo_bf(va0) + lo_bf(va1);
        a1 += hi_bf(va0) + hi_bf(va1);
    }
    for (; pN < enN; pN += 4) {
        int4 cb = *(const int4*)(csrN + pN);
        int cB0 = hf ? cb.y : cb.x;
        int cB1 = hf ? cb.w : cb.z;
        unsigned vb0 = xb32[cB0 * 32 + l5];
        unsigned vb1 = xb32[cB1 * 32 + l5];
        b0 += lo_bf(vb0) + lo_bf(vb1);
        b1 += hi_bf(vb0) + hi_bf(vb1);
    }
    a0 += __shfl_xor(a0, 32); a1 += __shfl_xor(a1, 32);
    b0 += __shfl_xor(b0, 32); b1 += __shfl_xor(b1, 32);
    float rP = 1.f / fmaxf((float)cP, 1.f), rN = 1.f / fmaxf((float)cN, 1.f);
    gP0 = a0 * rP; gP1 = a1 * rP;
    gN0 = b0 * rN; gN1 = b1 * rN;
}

__device__ inline void gd2q(const unsigned* __restrict__ hq32,
                            const int* __restrict__ csrP, int pP, int enP, int cP,
                            const int* __restrict__ csrN, int pN, int enN, int cN,
                            int hf, int l5,
                            float& gPp0, float& gPp1, float& gPn0, float& gPn1,
                            float& gNp0, float& gNp1, float& gNn0, float& gNn1) {
    float ap0 = 0.f, ap1 = 0.f, an0 = 0.f, an1 = 0.f;
    float bp0 = 0.f, bp1 = 0.f, bn0 = 0.f, bn1 = 0.f;
    while (pP < enP && pN < enN) {
        int4 ca = *(const int4*)(csrP + pP);
        int4 cb = *(const int4*)(csrN + pN);
        int cA0 = hf ? ca.y : ca.x;
        int cA1 = hf ? ca.w : ca.z;
        int cB0 = hf ? cb.y : cb.x;
        int cB1 = hf ? cb.w : cb.z;
        unsigned va0 = hq32[cA0 * 32 + l5];
        unsigned va1 = hq32[cA1 * 32 + l5];
        unsigned vb0 = hq32[cB0 * 32 + l5];
        unsigned vb1 = hq32[cB1 * 32 + l5];
        ap0 += __builtin_amdgcn_cvt_f32_fp8(va0, 0) + __builtin_amdgcn_cvt_f32_fp8(va1, 0);
        an0 += __builtin_amdgcn_cvt_f32_fp8(va0, 1) + __builtin_amdgcn_cvt_f32_fp8(va1, 1);
        ap1 += __builtin_amdgcn_cvt_f32_fp8(va0, 2) + __builtin_amdgcn_cvt_f32_fp8(va1, 2);
        an1 += __builtin_amdgcn_cvt_f32_fp8(va0, 3) + __builtin_amdgcn_cvt_f32_fp8(va1, 3);
        bp0 += __builtin_amdgcn_cvt_f32_fp8(vb0, 0) + __builtin_amdgcn_cvt_f32_fp8(vb1, 0);
        bn0 += __builtin_amdgcn_cvt_f32_fp8(vb0, 1) + __builtin_amdgcn_cvt_f32_fp8(vb1, 1);
        bp1 += __builtin_amdgcn_cvt_f32_fp8(vb0, 2) + __builtin_amdgcn_cvt_f32_fp8(vb1, 2);
        bn1 += __builtin_amdgcn_cvt_f32_fp8(vb0, 3) + __builtin_amdgcn_cvt_f32_fp8(vb1, 3);
        pP += 4; pN += 4;
    }
    for (; pP < enP; pP += 4) {
        int4 ca = *(const int4*)(csrP + pP);
        int cA0 = hf ? ca.y : ca.x;
        int cA1 = hf ? ca.w : ca.z;
        unsigned va0 = hq32[cA0 * 32 + l5];
        unsigned va1 = hq32[cA1 * 32 + l5];
        ap0 += __builtin_amdgcn_cvt_f32_fp8(va0, 0) + __builtin_amdgcn_cvt_f32_fp8(va1, 0);
        an0 += __builtin_amdgcn_cvt_f32_fp8(va0, 1) + __builtin_amdgcn_cvt_f32_fp8(va1, 1);
        ap1 += __builtin_amdgcn_cvt_f32_fp8(va0, 2) + __builtin_amdgcn_cvt_f32_fp8(va1, 2);
        an1 += __builtin_amdgcn_cvt_f32_fp8(va0, 3) + __builtin_amdgcn_cvt_f32_fp8(va1, 3);
    }
    for (; pN < enN; pN += 4) {
        int4 cb = *(const int4*)(csrN + pN);
        int cB0 = hf ? cb.y : cb.x;
        int cB1 = hf ? cb.w : cb.z;
        unsigned vb0 = hq32[cB0 * 32 + l5];
        unsigned vb1 = hq32[cB1 * 32 + l5];
        bp0 += __builtin_amdgcn_cvt_f32_fp8(vb0, 0) + __builtin_amdgcn_cvt_f32_fp8(vb1, 0);
        bn0 += __builtin_amdgcn_cvt_f32_fp8(vb0, 1) + __builtin_amdgcn_cvt_f32_fp8(vb1, 1);
        bp1 += __builtin_amdgcn_cvt_f32_fp8(vb0, 2) + __builtin_amdgcn_cvt_f32_fp8(vb1, 2);
        bn1 += __builtin_amdgcn_cvt_f32_fp8(vb0, 3) + __builtin_amdgcn_cvt_f32_fp8(vb1, 3);
    }
    ap0 += __shfl_xor(ap0, 32); ap1 += __shfl_xor(ap1, 32);
    an0 += __shfl_xor(an0, 32); an1 += __shfl_xor(an1, 32);
    bp0 += __shfl_xor(bp0, 32); bp1 += __shfl_xor(bp1, 32);
    bn0 += __shfl_xor(bn0, 32); bn1 += __shfl_xor(bn1, 32);
    float rP = 1.f / fmaxf((float)cP, 1.f), rN = 1.f / fmaxf((float)cN, 1.f);
    gPp0 = ap0 * rP; gPp1 = ap1 * rP; gPn0 = an0 * rP; gPn1 = an1 * rP;
    gNp0 = bp0 * rN; gNp1 = bp1 * rN; gNn0 = bn0 * rN; gNn1 = bn1 * rN;
}

__global__ __launch_bounds__(512) void base_both(
    const unsigned short* __restrict__ xb,
    const int* __restrict__ offP, const int* __restrict__ csrP,
    const int* __restrict__ offN, const int* __restrict__ csrN,
    const int* __restrict__ cntP, const int* __restrict__ cntN,
    const unsigned short* __restrict__ wt0,
    const float* __restrict__ bp0, const float* __restrict__ bn0,
    unsigned short* __restrict__ hboth, unsigned* __restrict__ hq32) {
    __shared__ unsigned short lds[64 * BSTR];
    int tid = threadIdx.x, lane = tid & 63, w = tid >> 6;
    int hf = lane >> 5, l5 = lane & 31;
    int base = blockIdx.x * 64;
    const unsigned* xb32 = (const unsigned*)xb;
    if (blockIdx.x == 0 && tid < 64) ((unsigned*)hboth)[N_NODES * 64 + tid] = 0u;
    if (blockIdx.x == 0 && tid < 32) hq32[N_NODES * 32 + tid] = 0u;
    for (int r = w * 8; r < w * 8 + 8; ++r) {
        int node = base + r;
        float gP0 = 0.f, gP1 = 0.f, gN0 = 0.f, gN1 = 0.f;
        unsigned sxv = 0;
        if (node < N_NODES) {
            gmb2w(xb32, csrP, offP[node], offP[node + 1], cntP[node],
                  csrN, offN[node], offN[node + 1], cntN[node], hf, l5,
                  gP0, gP1, gN0, gN1);
            sxv = xb32[node * 32 + l5];
        }
        unsigned* rp32 = (unsigned*)&lds[r * BSTR];
        if (hf == 0) {
            rp32[l5] = (unsigned)f2bf(gP0) | ((unsigned)f2bf(gP1) << 16);
            rp32[32 + l5] = sxv;
        } else {
            rp32[64 + l5] = (unsigned)f2bf(gN0) | ((unsigned)f2bf(gN1) << 16);
            rp32[96 + l5] = sxv;
        }
    }
    __syncthreads();
    int wu = __builtin_amdgcn_readfirstlane(w);
    int mt = wu >> 1, half = wu & 1;
    int l15 = lane & 15, kq = lane >> 4;
    const unsigned short* wbase = wt0 + half * 8192;
    f32x4 acc[4];
#pragma unroll
    for (int nt = 0; nt < 4; ++nt) acc[nt] = (f32x4){0.f, 0.f, 0.f, 0.f};
    const unsigned short* arow = &lds[(mt * 16 + l15) * BSTR + half * 128 + kq * 8];
#pragma unroll
    for (int ks = 0; ks < 4; ++ks) {
        sh8 a = *(const sh8*)(arow + ks * 32);
#pragma unroll
        for (int nt = 0; nt < 4; ++nt) {
            sh8 bf = *(const sh8*)(wbase + (nt * 16 + l15) * 128 + ks * 32 + kq * 8);
            acc[nt] = __builtin_amdgcn_mfma_f32_16x16x32_bf16(a, bf, acc[nt], 0, 0, 0);
        }
    }
    __syncthreads();
    float* ht = (float*)lds;  // [64][130]
    const float* bias = half ? bn0 : bp0;
#pragma unroll
    for (int nt = 0; nt < 4; ++nt) {
        int col = nt * 16 + l15;
        float bb = bias[col];
#pragma unroll
        for (int r = 0; r < 4; ++r) {
            int row = mt * 16 + kq * 4 + r;
            ht[row * 130 + half * 64 + col] = tanhf(acc[nt][r] + bb);
        }
    }
    __syncthreads();
    unsigned* hb32 = (unsigned*)hboth;
    for (int i = tid; i < 64 * 64; i += 512) {
        int rr = i >> 6, c = i & 63;
        int node = base + rr;
        if (node < N_NODES) {
            unsigned lo = f2bf(ht[rr * 130 + c]);
            unsigned hi = f2bf(ht[rr * 130 + 64 + c]);
            hb32[node * 64 + c] = lo | (hi << 16);
        }
    }
    for (int i = tid; i < 64 * 32; i += 512) {
        int rr = i >> 5, c2 = i & 31;
        int node = base + rr;
        if (node < N_NODES) {
            float hp0 = ht[rr * 130 + 2 * c2];
            float hn0 = ht[rr * 130 + 64 + 2 * c2];
            float hp1 = ht[rr * 130 + 2 * c2 + 1];
            float hn1 = ht[rr * 130 + 64 + 2 * c2 + 1];
            int lo = __builtin_amdgcn_cvt_pk_fp8_f32(hp0, hn0, 0, false);
            int q = __builtin_amdgcn_cvt_pk_fp8_f32(hp1, hn1, lo, true);
            hq32[node * 32 + c2] = (unsigned)q;
        }
    }
}

__global__ __launch_bounds__(512) void deep_both(
    const unsigned short* __restrict__ hb, const unsigned* __restrict__ hq32,
    const int* __restrict__ offP, const int* __restrict__ csrP,
    const int* __restrict__ offN, const int* __restrict__ csrN,
    const int* __restrict__ cntP, const int* __restrict__ cntN,
    const unsigned short* __restrict__ wt1,
    const float* __restrict__ bp1, const float* __restrict__ bn1,
    const float* __restrict__ Wreg, float* __restrict__ z,
    unsigned char* __restrict__ zq, float4* __restrict__ pnu) {
    __shared__ unsigned short lds[32 * DSTR];
    int tid = threadIdx.x, lane = tid & 63, w = tid >> 6;
    int hf = lane >> 5, l5 = lane & 31;
    int base = blockIdx.x * 32;
    const unsigned* hb32 = (const unsigned*)hb;
    for (int r = w * 4; r < w * 4 + 4; ++r) {
        int node = base + r;
        float gPp0, gPp1, gPn0, gPn1, gNp0, gNp1, gNn0, gNn1;
        gd2q(hq32, csrP, offP[node], offP[node + 1], cntP[node],
             csrN, offN[node], offN[node + 1], cntN[node], hf, l5,
             gPp0, gPp1, gPn0, gPn1, gNp0, gNp1, gNn0, gNn1);
        uint2 sv = *(const uint2*)(hb32 + node * 64 + l5 * 2);
        unsigned* rp32 = (unsigned*)&lds[r * DSTR];
        if (hf == 0) {
            rp32[l5] = (unsigned)f2bf(gPp0) | ((unsigned)f2bf(gPp1) << 16);
            rp32[32 + l5] = (unsigned)f2bf(gNn0) | ((unsigned)f2bf(gNn1) << 16);
            rp32[64 + l5] = (sv.x & 0xFFFFu) | ((sv.y & 0xFFFFu) << 16);
        } else {
            rp32[96 + l5] = (unsigned)f2bf(gPn0) | ((unsigned)f2bf(gPn1) << 16);
            rp32[128 + l5] = (unsigned)f2bf(gNp0) | ((unsigned)f2bf(gNp1) << 16);
            rp32[160 + l5] = (sv.x >> 16) | (sv.y & 0xFFFF0000u);
        }
    }
    __syncthreads();
    int wu = __builtin_amdgcn_readfirstlane(w);
    int mt = wu >> 2, half = (wu >> 1) & 1, nt = wu & 1;
    int l15 = lane & 15, kq = lane >> 4;
    const unsigned short* wbase = wt1 + half * 6144;
    f32x4 acc = (f32x4){0.f, 0.f, 0.f, 0.f};
    const unsigned short* arow = &lds[(mt * 16 + l15) * DSTR + half * 192 + kq * 8];
#pragma unroll
    for (int ks = 0; ks < 6; ++ks) {
        sh8 a = *(const sh8*)(arow + ks * 32);
        sh8 bf = *(const sh8*)(wbase + (nt * 16 + l15) * 192 + ks * 32 + kq * 8);
        acc = __builtin_amdgcn_mfma_f32_16x16x32_bf16(a, bf, acc, 0, 0, 0);
    }
    __syncthreads();
    float* ot = (float*)lds;  // [32][65]
    {
        const float* bias = half ? bn1 : bp1;
        int col = nt * 16 + l15;
        float bb = bias[col];
#pragma unroll
        for (int r = 0; r < 4; ++r) {
            int row = mt * 16 + kq * 4 + r;
            ot[row * 65 + half * 32 + col] = tanhf(acc[r] + bb);
        }
    }
    __syncthreads();
    for (int r = w * 4; r < w * 4 + 4; ++r) {
        int node = base + r;
        float v = ot[r * 65 + lane];
        z[node * 64 + lane] = v;
        int pq = __builtin_amdgcn_cvt_pk_fp8_f32(v, v, 0, false);
        zq[node * 64 + lane] = (unsigned char)(pq & 0xFF);
        float vq = __builtin_amdgcn_cvt_f32_fp8(pq, 0);
        float u0 = vq * Wreg[lane * 2 + 0];
        float u1 = vq * Wreg[lane * 2 + 1];
        float s = vq * vq;
#pragma unroll
        for (int off = 32; off; off >>= 1) {
            u0 += __shfl_xor(u0, off);
            u1 += __shfl_xor(u1, off);
            s += __shfl_xor(s, off);
        }
        if (lane == 0) {
            float4 su = {u0, u1, s, 0.f};
            pnu[node] = su;
        }
    }
}

// 4-lane edge groups: sj/sk/v computed from rows; only pnu[i] (L2-local) loaded
__global__ __launch_bounds__(256) void loss7_kernel(
    const unsigned char* __restrict__ zq, const float4* __restrict__ pnu,
    const unsigned* __restrict__ wvb, const int4* __restrict__ eidx, float* acc) {
    int tid = threadIdx.x;
    int lane = tid & 63;
    int g = lane >> 2, sub = lane & 3;
    int wid = (blockIdx.x * 256 + tid) >> 6;
    int nw = (gridDim.x * 256) >> 6;
    // per-lane Wreg v-cols for dims [sub*16, sub*16+16), packed {v0,v1} bf16
    uint4 wv4[4];
#pragma unroll
    for (int t = 0; t < 4; ++t) wv4[t] = ((const uint4*)wvb)[sub * 4 + t];
    float s_p = 0.f, s_n = 0.f, s_r = 0.f;
    const float q = 0.25f;
    for (int eb = wid * 32; eb < EP_N + EN_N; eb += nw * 32) {
        int eA = eb + g, eB = eb + 16 + g;
        bool vA = eA < EP_N + EN_N, vB = eB < EP_N + EN_N;
        bool pA = eA < EP_N, pB = eB < EP_N;
        int4 qA = eidx[vA ? eA : 0];
        int4 qB = eidx[vB ? eB : 0];
        uint4 ziA = *(const uint4*)(zq + ((long long)qA.x << 6) + (sub << 4));
        uint4 zjA = *(const uint4*)(zq + ((long long)qA.y << 6) + (sub << 4));
        uint4 zkA = *(const uint4*)(zq + ((long long)qA.z << 6) + (sub << 4));
        uint4 ziB = *(const uint4*)(zq + ((long long)qB.x << 6) + (sub << 4));
        uint4 zjB = *(const uint4*)(zq + ((long long)qB.y << 6) + (sub << 4));
        uint4 zkB = *(const uint4*)(zq + ((long long)qB.z << 6) + (sub << 4));
        float4 uA = pnu[qA.x];
        float4 uB = pnu[qB.x];
        float d1A = 0.f, d2A = 0.f, sjA = 0.f, skA = 0.f, v0A = 0.f, v1A = 0.f;
        {
            float fi[16], fj[16], fk[16];
            cvt16(ziA, fi); cvt16(zjA, fj); cvt16(zkA, fk);
#pragma unroll
            for (int t = 0; t < 16; ++t) {
                d1A = fmaf(fi[t], fj[t], d1A);
                d2A = fmaf(fj[t], fk[t], d2A);
                sjA = fmaf(fj[t], fj[t], sjA);
                skA = fmaf(fk[t], fk[t], skA);
                unsigned wp = (&wv4[t >> 2].x)[t & 3];
                v0A = fmaf(fj[t], lo_bf(wp), v0A);
                v1A = fmaf(fj[t], hi_bf(wp), v1A);
            }
        }
        float d1B = 0.f, d2B = 0.f, sjB = 0.f, skB = 0.f, v0B = 0.f, v1B = 0.f;
        {
            float fi[16], fj[16], fk[16];
            cvt16(ziB, fi); cvt16(zjB, fj); cvt16(zkB, fk);
#pragma unroll
            for (int t = 0; t < 16; ++t) {
                d1B = fmaf(fi[t], fj[t], d1B);
                d2B = fmaf(fj[t], fk[t], d2B);
                sjB = fmaf(fj[t], fj[t], sjB);
                skB = fmaf(fk[t], fk[t], skB);
                unsigned wp = (&wv4[t >> 2].x)[t & 3];
                v0B = fmaf(fj[t], lo_bf(wp), v0B);
                v1B = fmaf(fj[t], hi_bf(wp), v1B);
            }
        }
#pragma unroll
        for (int off = 1; off < 4; off <<= 1) {
            d1A += __shfl_xor(d1A, off);
            d2A += __shfl_xor(d2A, off);
            sjA += __shfl_xor(sjA, off);
            skA += __shfl_xor(skA, off);
            v0A += __shfl_xor(v0A, off);
            v1A += __shfl_xor(v1A, off);
            d1B += __shfl_xor(d1B, off);
            d2B += __shfl_xor(d2B, off);
            sjB += __shfl_xor(sjB, off);
            skB += __shfl_xor(skB, off);
            v0B += __shfl_xor(v0B, off);
            v1B += __shfl_xor(v1B, off);
        }
        if (vA) {
            float nij = uA.z + sjA - 2.f * d1A;
            float nik = sjA + skA - 2.f * d2A;
            float tri = fmaxf(nij - nik, 0.f);
            float l0 = uA.x + v0A, l1 = uA.y + v1A;
            float m = fmaxf(l0, l1);
            float lse = m + logf(expf(l0 - m) + expf(l1 - m));
            s_r += (lse - (qA.w ? l1 : l0)) * q;
            if (pA) s_p += tri * q; else s_n += tri * q;
        }
        if (vB) {
            float nij = uB.z + sjB - 2.f * d1B;
            float nik = sjB + skB - 2.f * d2B;
            float tri = fmaxf(nij - nik, 0.f);
            float l0 = uB.x + v0B, l1 = uB.y + v1B;
            float m = fmaxf(l0, l1);
            float lse = m + logf(expf(l0 - m) + expf(l1 - m));
            s_r += (lse - (qB.w ? l1 : l0)) * q;
            if (pB) s_p += tri * q; else s_n += tri * q;
        }
    }
#pragma unroll
    for (int off = 32; off; off >>= 1) {
        s_p += __shfl_xor(s_p, off);
        s_n += __shfl_xor(s_n, off);
        s_r += __shfl_xor(s_r, off);
    }
    __shared__ float red[3][4];
    int w = tid >> 6;
    if (lane == 0) {
        red[0][w] = s_p; red[1][w] = s_n; red[2][w] = s_r;
    }
    __syncthreads();
    if (tid == 0) {
        atomicAdd(&acc[0], red[0][0] + red[0][1] + red[0][2] + red[0][3]);
        atomicAdd(&acc[1], red[1][0] + red[1][1] + red[1][2] + red[1][3]);
        atomicAdd(&acc[2], red[2][0] + red[2][1] + red[2][2] + red[2][3]);
    }
}

__global__ void finalize_kernel(const float* __restrict__ acc, float* out) {
    out[0] = acc[2] / (float)(EP_N + EN_N) +
             1.0f * (acc[0] / (float)EP_N + acc[1] / (float)EN_N);
}

extern "C" void kernel_launch(void* const* d_in, const int* in_sizes, int n_in,
                              void* d_out, int out_size, void* d_ws, size_t ws_size,
                              hipStream_t stream) {
    const float* X = (const float*)d_in[0];
    const float* W_pos0 = (const float*)d_in[1];
    const float* b_pos0 = (const float*)d_in[2];
    const float* W_neg0 = (const float*)d_in[3];
    const float* b_neg0 = (const float*)d_in[4];
    const float* W_pos1 = (const float*)d_in[5];
    const float* b_pos1 = (const float*)d_in[6];
    const float* W_neg1 = (const float*)d_in[7];
    const float* b_neg1 = (const float*)d_in[8];
    const float* W_reg = (const float*)d_in[9];
    const int* pe = (const int*)d_in[10];
    const int* ne = (const int*)d_in[11];
    const int* target = (const int*)d_in[12];
    const int* ps = (const int*)d_in[13];
    const int* ns = (const int*)d_in[14];
    float* out = (float*)d_out;
    float* ws = (float*)d_ws;
    int* wsi = (int*)d_ws;

    float* acc = ws + ACC_OFF;
    int* cntP = wsi + I_CNTP;
    int* cntN = wsi + I_CNTN;
    int* curP = wsi + I_CURP;
    int* curN = wsi + I_CURN;
    int* offP = wsi + I_OFFP;
    int* offN = wsi + I_OFFN;
    int* offPc = wsi + I_OFFPC;
    int* offNc = wsi + I_OFFNC;
    int* csrP = wsi + I_CSRP;
    int* csrN = wsi + I_CSRN;
    int* part = wsi + I_PART;
    int4* eidx = (int4*)(wsi + I_EIDX);
    unsigned short* xb = (unsigned short*)(ws + F_XB);
    unsigned short* hboth = (unsigned short*)(ws + F_HB);
    unsigned* hq32 = (unsigned*)(ws + F_HQ);
    float4* pnu = (float4*)(ws + F_PNU);
    unsigned char* zq = (unsigned char*)(ws + F_ZQ);
    unsigned short* wt = (unsigned short*)(ws + F_WT);
    const unsigned* wvb = (const unsigned*)(wt + 28672);
    float* z = out + 1;

    hipMemsetAsync(ws, 0, (size_t)(16 + 4 * N_NODES) * sizeof(float), stream);

    prep_kernel<<<XB_BLKS + WP_BLKS + CNT_BLKS, 256, 0, stream>>>(
        X, xb, W_pos0, W_neg0, W_pos1, W_neg1, W_reg, wt, pe, ne, cntP, cntN);
    scan_p1<<<2 * SBLK, 512, 0, stream>>>(cntP, cntN, part);
    scan_p2<<<1, 1024, 0, stream>>>(part);
    scan_p3<<<2 * SBLK, 512, 0, stream>>>(cntP, cntN, part, offP, offN,
                                          offPc, offNc, csrP, csrN);
    fill_kernel<<<(EP_N + EN_N + 255) / 256, 256, 0, stream>>>(
        pe, ne, offP, offN, offPc, offNc, ps, ns, target,
        curP, curN, csrP, csrN, eidx);

    base_both<<<NODE_BLOCKS, 512, 0, stream>>>(xb, offP, csrP, offN, csrN, cntP, cntN,
                                               wt, b_pos0, b_neg0, hboth, hq32);
    deep_both<<<DEEP_BLOCKS, 512, 0, stream>>>(hboth, hq32, offP, csrP, offN, csrN,
                                               cntP, cntN, wt + 16384, b_pos1, b_neg1,
                                               W_reg, z, zq, pnu);

    loss7_kernel<<<2048, 256, 0, stream>>>(zq, pnu, wvb, eidx, acc);
    finalize_kernel<<<1, 1, 0, stream>>>(acc, out);
}